// Round 2
// baseline (230.853 us; speedup 1.0000x reference)
//
#include <hip/hip_runtime.h>
#include <hip/hip_bf16.h>
#include <math.h>

// Sizes: B=16, N=64, nE=128, H=128, LAT=128, NS=64, NV=32, INV=96, D_NODE=160
#define SQRT3F 1.7320508075688772f
#define ALPHAF 0.10206207261596577f  // 1/sqrt(96)
#define PIF 3.14159265358979323846f

typedef short v8s __attribute__((ext_vector_type(8)));
typedef float v4f __attribute__((ext_vector_type(4)));

__device__ __forceinline__ float silu_f(float x) {
  return x / (1.0f + __expf(-x));
}
__device__ __forceinline__ float sigmoid_f(float x) {
  return 1.0f / (1.0f + __expf(-x));
}
__device__ __forceinline__ unsigned short f2bf(float f) {
  unsigned int u = __float_as_uint(f);
  unsigned int r = (u + 0x7fffu + ((u >> 16) & 1u)) >> 16;
  return (unsigned short)r;
}
__device__ __forceinline__ float bf2f(unsigned short h) {
  return __uint_as_float(((unsigned int)h) << 16);
}
__device__ __forceinline__ void split_trunc(float x, short* h, short* l) {
  unsigned int u = __float_as_uint(x);
  unsigned short hs = (unsigned short)(u >> 16);
  float r = x - __uint_as_float((unsigned int)hs << 16);
  *h = (short)hs;
  *l = (short)(__float_as_uint(r) >> 16);
}

__device__ __forceinline__ void pack_frag(const float* __restrict__ W, int s0,
                                          unsigned short* __restrict__ fh,
                                          unsigned short* __restrict__ fl) {
  const int lane = s0 & 63;
  const int t = (s0 >> 6) & 7;
  const int ks = s0 >> 9;
  const int kbase = ks * 32 + (lane >> 4) * 8;
  const int n = t * 16 + (lane & 15);
  unsigned short hv[8], lv[8];
  #pragma unroll
  for (int j = 0; j < 8; ++j) {
    float w = W[(size_t)(kbase + j) * 128 + n];
    unsigned short h = f2bf(w);
    hv[j] = h;
    lv[j] = f2bf(w - bf2f(h));
  }
  *(uint4*)&fh[(size_t)s0 * 8] = *(uint4*)hv;
  *(uint4*)&fl[(size_t)s0 * 8] = *(uint4*)lv;
}

// ---------------------------------------------------------------------------
// K_FRONT: merged castw2 (blocks 0..575) + prep (576..1087, 2 nodes/block)
// + castw1/packout/Pe (1088..1181). (kept from R16 — saved ~10us)
// ---------------------------------------------------------------------------
__global__ void __launch_bounds__(256) k_front(
    const float* __restrict__ W2, unsigned short* __restrict__ W2fh,
    unsigned short* __restrict__ W2fl,
    const float* __restrict__ hf, const int* __restrict__ z,
    const float* __restrict__ pos, const float* __restrict__ z_emb,
    const float* __restrict__ vwW0, const float* __restrict__ vwb0,
    const float* __restrict__ vwW1, const float* __restrict__ vwb1,
    const float* __restrict__ scW0,
    unsigned short* __restrict__ hTh, unsigned short* __restrict__ hTl,
    float* __restrict__ Pn, float* __restrict__ Pa,
    float* __restrict__ xvu, float* __restrict__ y1cw,
    const float* __restrict__ scW1,
    unsigned short* __restrict__ W1fh, unsigned short* __restrict__ W1fl,
    const float* __restrict__ oW0, const float* __restrict__ oW1,
    const float* __restrict__ oW2,
    unsigned short* __restrict__ O0h, unsigned short* __restrict__ O0l,
    unsigned short* __restrict__ O1h, unsigned short* __restrict__ O1l,
    unsigned short* __restrict__ O2h, unsigned short* __restrict__ O2l,
    const float* __restrict__ e_feat, const float* __restrict__ scb0,
    float* __restrict__ Pe) {
  const int bid = blockIdx.x;
  const int tid = threadIdx.x;
  __shared__ float S[2304];

  if (bid < 576) {
    const int T = bid;
    float (*Tl)[17] = (float(*)[17])S;
    for (int idx = tid; idx < 2048; idx += 256) {
      int k = idx >> 4, cc = idx & 15;
      Tl[k][cc] = W2[(size_t)k * 9216 + T * 16 + cc];
    }
    __syncthreads();
    const int ks = tid >> 6, lane = tid & 63;
    const int q = lane >> 4, cq = lane & 15;
    const int k0 = ks * 32 + q * 8;
    unsigned short hv[8], lv[8];
    #pragma unroll
    for (int j = 0; j < 8; ++j) {
      float wv = Tl[k0 + j][cq];
      unsigned short h = f2bf(wv);
      hv[j] = h;
      lv[j] = f2bf(wv - bf2f(h));
    }
    size_t base = ((size_t)(T * 4 + ks) * 64 + lane) * 8;
    *(uint4*)&W2fh[base] = *(uint4*)hv;
    *(uint4*)&W2fl[base] = *(uint4*)lv;
  } else if (bid < 1088) {
    const int sb = tid >> 7;
    const int t = tid & 127;
    const int g = (bid - 576) * 2 + sb;
    const int b = g >> 6, n = g & 63;
    float* vin  = S + sb * 1152;
    float* invn = vin + 64;
    float* h0   = invn + 96;
    float* uS   = h0 + 128;
    float* rS   = uS + 3;

    if (t == 0) {
      float px = pos[g * 3 + 0] - pos[(b * 64) * 3 + 0];
      float py = pos[g * 3 + 1] - pos[(b * 64) * 3 + 1];
      float pz = pos[g * 3 + 2] - pos[(b * 64) * 3 + 2];
      float r = sqrtf(px * px + py * py + pz * pz + 1e-12f);
      float rm = fmaxf(r, 1e-8f);
      uS[0] = px / rm; uS[1] = py / rm; uS[2] = pz / rm;
      rS[0] = r;
    }
    __syncthreads();
    const float r = rS[0];

    if (t < 32) {
      const float delta = 6.0f / 31.0f;
      const float gamma = 1.0f / (delta * delta + 1e-12f);
      int zi = z[g];
      vin[t] = z_emb[zi * 32 + t];
      float rc = fminf(r, 6.0f);
      float d = rc - (float)t * delta;
      vin[32 + t] = __expf(-gamma * d * d);
      float a = hf[g * 160 + 64 + t * 3 + 0] * uS[0]
              + hf[g * 160 + 64 + t * 3 + 1] * uS[1]
              + hf[g * 160 + 64 + t * 3 + 2] * uS[2];
      xvu[g * 32 + t] = a;
    }
    if (t < 96) {
      if (t < 64) {
        invn[t] = hf[g * 160 + t];
      } else {
        int o = t - 64;
        float v0 = hf[g * 160 + 64 + o * 3 + 0];
        float v1 = hf[g * 160 + 64 + o * 3 + 1];
        float v2 = hf[g * 160 + 64 + o * 3 + 2];
        invn[t] = sqrtf((v0 * v0 + v1 * v1 + v2 * v2) * (1.0f / 3.0f) + 1e-8f);
      }
    }
    if (t == 0) {
      float cw = 0.0f;
      if (r <= 6.0f && n != 0) cw = 0.5f * (cosf(PIF * r * (1.0f / 6.0f)) + 1.0f);
      y1cw[g * 4 + 0] = SQRT3F * uS[0];
      y1cw[g * 4 + 1] = SQRT3F * uS[1];
      y1cw[g * 4 + 2] = SQRT3F * uS[2];
      y1cw[g * 4 + 3] = cw;
    }
    __syncthreads();

    {
      float a = vwb0[t];
      #pragma unroll 8
      for (int k = 0; k < 64; ++k) a = fmaf(vin[k], vwW0[k * 128 + t], a);
      h0[t] = silu_f(a);
    }
    __syncthreads();
    {
      float a = vwb1[t];
      #pragma unroll 8
      for (int k = 0; k < 128; ++k) a = fmaf(h0[k], vwW1[k * 128 + t], a);
      float hv = silu_f(a);
      unsigned short hh = f2bf(hv);
      hTh[(size_t)g * 128 + t] = hh;
      hTl[(size_t)g * 128 + t] = f2bf(hv - bf2f(hh));
    }
    {
      float p = 0.0f;
      #pragma unroll 8
      for (int k = 0; k < 96; ++k) p = fmaf(invn[k], scW0[(96 + k) * 128 + t], p);
      #pragma unroll 8
      for (int k = 0; k < 64; ++k) p = fmaf(vin[k], scW0[(192 + k) * 128 + t], p);
      Pn[(size_t)g * 128 + t] = p;
    }
    if (n == 0) {
      float p = 0.0f;
      #pragma unroll 8
      for (int k = 0; k < 96; ++k) p = fmaf(invn[k], scW0[k * 128 + t], p);
      Pa[b * 128 + t] = p;
    }
  } else {
    const int sb = bid - 1088;
    if (sb < 8) {
      pack_frag(scW1, sb * 256 + tid, W1fh, W1fl);
    } else if (sb < 30) {
      const int s = (sb - 8) * 256 + tid;
      if (s >= 5632) return;
      if (s < 1536)       pack_frag(oW0, s, O0h, O0l);
      else if (s < 3584)  pack_frag(oW1, s - 1536, O1h, O1l);
      else                pack_frag(oW2, s - 3584, O2h, O2l);
    } else {
      const int e = (sb - 30) * 2 + (tid >> 7);
      const int t = tid & 127;
      float a = scb0[t];
      #pragma unroll
      for (int k = 0; k < 16; ++k)
        a = fmaf(e_feat[e * 16 + k], scW0[(256 + k) * 128 + t], a);
      Pe[e * 128 + t] = a;
    }
  }
}

// ---------------------------------------------------------------------------
// K2 v13: chain-split MFMA GEMM. grid=1024: cs=bid&31 (p8=bid&7 stays
// XCD-pinned), g0=((bid>>5)&15)*64, half=bid>>9. Half 0 runs tiles 0..7
// (racc1 only), half 1 runs tiles 8..17 (racc2/3/4). Correct because the
// values8 accumulation is linear — each half atomically adds its partial
// raccs. Changes vs v12: (a) epilogue is direct register->atomicAdd (drops
// 48KB valsS/svS LDS -> 16KB total, same atomic count class); (b) tile-
// invariant hf/xvu/b2 scalar L2 loads hoisted out of the barrier chain;
// (c) per-block chain is 8-10 barriers instead of 18, 4 blocks/CU assigned.
// R16 lesson respected: per-block MFMA-per-staging-round ratio unchanged;
// only the chain length and block count changed.
// ---------------------------------------------------------------------------
__device__ __forceinline__ int tile_of(int cs, int t) {
  if (t < 8)  return cs * 8 + t;
  if (t < 12) return 256 + cs * 4 + (t - 8);
  if (t < 14) return 384 + cs * 2 + (t - 12);
  return 448 + cs * 4 + (t - 14);
}

template <int TB, int TN>
__device__ __forceinline__ void tp_body(
    unsigned short (* __restrict__ BstH)[256][8],
    unsigned short (* __restrict__ BstL)[256][8],
    const unsigned short* __restrict__ hTh, const unsigned short* __restrict__ hTl,
    const unsigned short* __restrict__ W2fh, const unsigned short* __restrict__ W2fl,
    const float* __restrict__ b2, const float* __restrict__ hf,
    const float* __restrict__ xvu, const float* __restrict__ y1cw,
    float* __restrict__ values8, int cs, int g0, int p8) {
  const int tid = threadIdx.x;
  const int w = tid >> 6, l = tid & 63;
  const int q = l >> 4, cq = l & 15;
  const int nrow = w * 16 + q * 4;

  const int anode = g0 + w * 16 + cq;
  v8s ah0 = *(const v8s*)&hTh[(size_t)anode * 128 + 0 * 32 + q * 8];
  v8s ah1 = *(const v8s*)&hTh[(size_t)anode * 128 + 1 * 32 + q * 8];
  v8s ah2 = *(const v8s*)&hTh[(size_t)anode * 128 + 2 * 32 + q * 8];
  v8s ah3 = *(const v8s*)&hTh[(size_t)anode * 128 + 3 * 32 + q * 8];
  v8s al0 = *(const v8s*)&hTl[(size_t)anode * 128 + 0 * 32 + q * 8];
  v8s al1 = *(const v8s*)&hTl[(size_t)anode * 128 + 1 * 32 + q * 8];
  v8s al2 = *(const v8s*)&hTl[(size_t)anode * 128 + 2 * 32 + q * 8];
  v8s al3 = *(const v8s*)&hTl[(size_t)anode * 128 + 3 * 32 + q * 8];

  // tile-invariant operand hoists (were per-tile scalar L2 loads in v12)
  float hfa[2][4], hfv3[4][3], xv4[4];
  #pragma unroll
  for (int r = 0; r < 4; ++r) {
    const float* hrow = hf + (size_t)(g0 + nrow + r) * 160;
    hfa[0][r] = hrow[cs * 2];
    hfa[1][r] = hrow[cs * 2 + 1];
    if (TB != 0) {
      hfv3[r][0] = hrow[64 + 3 * cs + 0];
      hfv3[r][1] = hrow[64 + 3 * cs + 1];
      hfv3[r][2] = hrow[64 + 3 * cs + 2];
      xv4[r] = xvu[(size_t)(g0 + nrow + r) * 32 + cs];
    }
  }
  float bjv[TN];
  #pragma unroll
  for (int j = 0; j < TN; ++j) bjv[j] = b2[tile_of(cs, TB + j) * 16 + cq];

  float racc1[4][4] = {{0.f}};
  float racc2[2][4] = {{0.f}};
  float racc3[2][4][3] = {{{0.f}}};
  float racc4[4][4] = {{0.f}};

  {
    const int T = tile_of(cs, TB);
    uint4 gh = *(const uint4*)&W2fh[(size_t)T * 2048 + tid * 8];
    uint4 gl = *(const uint4*)&W2fl[(size_t)T * 2048 + tid * 8];
    *(uint4*)&BstH[0][tid][0] = gh;
    *(uint4*)&BstL[0][tid][0] = gl;
  }
  __syncthreads();

  #pragma unroll
  for (int j = 0; j < TN; ++j) {
    const int buf = j & 1;
    const int t = TB + j;  // compile-time after unroll
    uint4 gh, gl;
    if (j < TN - 1) {
      const int Tn = tile_of(cs, t + 1);
      gh = *(const uint4*)&W2fh[(size_t)Tn * 2048 + tid * 8];
      gl = *(const uint4*)&W2fl[(size_t)Tn * 2048 + tid * 8];
    }

    v8s bh0 = *(const v8s*)&BstH[buf][0 * 64 + l][0];
    v8s bh1 = *(const v8s*)&BstH[buf][1 * 64 + l][0];
    v8s bh2 = *(const v8s*)&BstH[buf][2 * 64 + l][0];
    v8s bh3 = *(const v8s*)&BstH[buf][3 * 64 + l][0];
    v8s bl0 = *(const v8s*)&BstL[buf][0 * 64 + l][0];
    v8s bl1 = *(const v8s*)&BstL[buf][1 * 64 + l][0];
    v8s bl2 = *(const v8s*)&BstL[buf][2 * 64 + l][0];
    v8s bl3 = *(const v8s*)&BstL[buf][3 * 64 + l][0];

    v4f a0 = (v4f){0.f, 0.f, 0.f, 0.f};
    v4f a1 = (v4f){0.f, 0.f, 0.f, 0.f};
    v4f a2 = (v4f){0.f, 0.f, 0.f, 0.f};
    a0 = __builtin_amdgcn_mfma_f32_16x16x32_bf16(ah0, bh0, a0, 0, 0, 0);
    a1 = __builtin_amdgcn_mfma_f32_16x16x32_bf16(al0, bh0, a1, 0, 0, 0);
    a2 = __builtin_amdgcn_mfma_f32_16x16x32_bf16(ah0, bl0, a2, 0, 0, 0);
    a0 = __builtin_amdgcn_mfma_f32_16x16x32_bf16(ah1, bh1, a0, 0, 0, 0);
    a1 = __builtin_amdgcn_mfma_f32_16x16x32_bf16(al1, bh1, a1, 0, 0, 0);
    a2 = __builtin_amdgcn_mfma_f32_16x16x32_bf16(ah1, bl1, a2, 0, 0, 0);
    a0 = __builtin_amdgcn_mfma_f32_16x16x32_bf16(ah2, bh2, a0, 0, 0, 0);
    a1 = __builtin_amdgcn_mfma_f32_16x16x32_bf16(al2, bh2, a1, 0, 0, 0);
    a2 = __builtin_amdgcn_mfma_f32_16x16x32_bf16(ah2, bl2, a2, 0, 0, 0);
    a0 = __builtin_amdgcn_mfma_f32_16x16x32_bf16(ah3, bh3, a0, 0, 0, 0);
    a1 = __builtin_amdgcn_mfma_f32_16x16x32_bf16(al3, bh3, a1, 0, 0, 0);
    a2 = __builtin_amdgcn_mfma_f32_16x16x32_bf16(ah3, bl3, a2, 0, 0, 0);
    a0 += a1; a0 += a2;
    const float bj = bjv[j];
    v4f tp = a0;
    tp[0] += bj; tp[1] += bj; tp[2] += bj; tp[3] += bj;

    if (t < 8) {
      const int ii = t >> 2;
      const int m = t & 3;
      #pragma unroll
      for (int r = 0; r < 4; ++r)
        racc1[m][r] = fmaf(hfa[ii][r], tp[r], racc1[m][r]);
    } else if (t < 12) {
      const int ii = (t - 8) >> 1;
      const int m = (t - 8) & 1;
      #pragma unroll
      for (int r = 0; r < 4; ++r)
        racc2[m][r] = fmaf(hfa[ii][r], tp[r], racc2[m][r]);
    } else if (t < 14) {
      const int m = (t - 12) & 1;
      #pragma unroll
      for (int r = 0; r < 4; ++r)
        #pragma unroll
        for (int cc = 0; cc < 3; ++cc)
          racc3[m][r][cc] = fmaf(hfv3[r][cc], tp[r], racc3[m][r][cc]);
    } else {
      const int m = (t - 14) & 3;
      #pragma unroll
      for (int r = 0; r < 4; ++r)
        racc4[m][r] = fmaf(xv4[r], tp[r], racc4[m][r]);
    }

    if (j < TN - 1) {
      const int nbuf = buf ^ 1;
      *(uint4*)&BstH[nbuf][tid][0] = gh;
      *(uint4*)&BstL[nbuf][tid][0] = gl;
    }
    __syncthreads();
  }

  // epilogue: direct atomics from registers (partials; linearity makes the
  // half-split correct). half0: 16/thread, half1: 40/thread.
  float* vtgt = values8 + (size_t)p8 * 163840;
  #pragma unroll
  for (int r = 0; r < 4; ++r) {
    const int n = nrow + r;
    float* vrow = vtgt + (size_t)(g0 + n) * 160;
    if (TB == 0) {
      #pragma unroll
      for (int m = 0; m < 4; ++m)
        atomicAdd(&vrow[m * 16 + cq], racc1[m][r]);
    } else {
      float4 y1v = *(const float4*)&y1cw[(size_t)(g0 + n) * 4];
      float y1a[3] = {y1v.x, y1v.y, y1v.z};
      #pragma unroll
      for (int m = 0; m < 4; ++m)
        atomicAdd(&vrow[m * 16 + cq], racc4[m][r]);
      #pragma unroll
      for (int m = 0; m < 2; ++m) {
        const int o = m * 16 + cq;
        #pragma unroll
        for (int cc = 0; cc < 3; ++cc)
          atomicAdd(&vrow[64 + 3 * o + cc],
                    racc3[m][r][cc] + racc2[m][r] * y1a[cc]);
      }
    }
  }
}

__global__ void __launch_bounds__(256) k_tp(
    const unsigned short* __restrict__ hTh, const unsigned short* __restrict__ hTl,
    const unsigned short* __restrict__ W2fh, const unsigned short* __restrict__ W2fl,
    const float* __restrict__ b2, const float* __restrict__ hf,
    const float* __restrict__ xvu, const float* __restrict__ y1cw,
    float* __restrict__ values8) {
  const int bid = blockIdx.x;
  const int cs = bid & 31;
  const int g0 = ((bid >> 5) & 15) * 64;
  const int half = bid >> 9;
  const int p8 = cs & 7;

  __shared__ unsigned short BstH[2][256][8];
  __shared__ unsigned short BstL[2][256][8];

  if (half == 0)
    tp_body<0, 8>(BstH, BstL, hTh, hTl, W2fh, W2fl, b2, hf, xvu, y1cw,
                  values8, cs, g0, p8);
  else
    tp_body<8, 10>(BstH, BstL, hTh, hTl, W2fh, W2fl, b2, hf, xvu, y1cw,
                   values8, cs, g0, p8);
}

// ---------------------------------------------------------------------------
// K2b: values[n][d] = ALPHAF * sum_p values8[p][n][d]. grid=160, block=256.
// ---------------------------------------------------------------------------
__global__ void __launch_bounds__(256) k_reduce(
    const float* __restrict__ values8, float* __restrict__ values) {
  const int s = blockIdx.x * 256 + threadIdx.x;
  float4 acc = make_float4(0.f, 0.f, 0.f, 0.f);
  #pragma unroll
  for (int p = 0; p < 8; ++p) {
    float4 v = *(const float4*)&values8[(size_t)p * 163840 + s * 4];
    acc.x += v.x; acc.y += v.y; acc.z += v.z; acc.w += v.w;
  }
  acc.x *= ALPHAF; acc.y *= ALPHAF; acc.z *= ALPHAF; acc.w *= ALPHAF;
  *(float4*)&values[(size_t)s * 4] = acc;
}

// ---------------------------------------------------------------------------
// K3 v6: MLP-only gate kernel (unchanged from R1). grid=1024, 2 energies/
// block. Norm folded into the gate write via butterfly shfl_xor.
// ---------------------------------------------------------------------------
__global__ void __launch_bounds__(256, 4) k_gate(
    const float* __restrict__ Pa, const float* __restrict__ Pe,
    const float* __restrict__ Pn,
    const unsigned short* __restrict__ W1fh, const unsigned short* __restrict__ W1fl,
    const float* __restrict__ b1, const float* __restrict__ W2v,
    const float* __restrict__ b2s, const float* __restrict__ y1cw,
    float* __restrict__ gate) {
  const int bid = blockIdx.x;
  const int b = bid >> 6;
  const int e0 = (bid & 63) * 2, e1 = e0 + 1;
  const int tid = threadIdx.x;

  __shared__ float Prow0[128], Prow1[128];
  __shared__ float gpre[2][64];

  if (tid < 128) {
    float pa = Pa[b * 128 + tid];
    Prow0[tid] = pa + Pe[e0 * 128 + tid];
    Prow1[tid] = pa + Pe[e1 * 128 + tid];
  }
  __syncthreads();

  const int w = tid >> 6, l = tid & 63;
  const int q = l >> 4, cq = l & 15;
  const int node = w * 16 + cq;
  const float* pnrow = Pn + (size_t)(b * 64 + node) * 128;

  v4f acc0[8], acc1[8];
  #pragma unroll
  for (int t = 0; t < 8; ++t) {
    acc0[t] = (v4f){0.f, 0.f, 0.f, 0.f};
    acc1[t] = (v4f){0.f, 0.f, 0.f, 0.f};
  }

  #pragma unroll
  for (int ks = 0; ks < 4; ++ks) {
    const int k0 = ks * 32 + q * 8;
    float4 p0 = *(const float4*)(pnrow + k0);
    float4 p1 = *(const float4*)(pnrow + k0 + 4);
    float pv[8] = {p0.x, p0.y, p0.z, p0.w, p1.x, p1.y, p1.z, p1.w};
    float4 r00 = *(const float4*)(&Prow0[k0]);
    float4 r01 = *(const float4*)(&Prow0[k0 + 4]);
    float4 r10 = *(const float4*)(&Prow1[k0]);
    float4 r11 = *(const float4*)(&Prow1[k0 + 4]);
    float rv0[8] = {r00.x, r00.y, r00.z, r00.w, r01.x, r01.y, r01.z, r01.w};
    float rv1[8] = {r10.x, r10.y, r10.z, r10.w, r11.x, r11.y, r11.z, r11.w};
    v8s a0h, a0l, a1h, a1l;
    #pragma unroll
    for (int j = 0; j < 8; ++j) {
      short hs, ls;
      split_trunc(silu_f(pv[j] + rv0[j]), &hs, &ls);
      a0h[j] = hs; a0l[j] = ls;
      split_trunc(silu_f(pv[j] + rv1[j]), &hs, &ls);
      a1h[j] = hs; a1l[j] = ls;
    }
    #pragma unroll
    for (int t = 0; t < 8; ++t) {
      const size_t fb = (size_t)((ks * 8 + t) * 64 + l) * 8;
      v8s bh = *(const v8s*)&W1fh[fb];
      v8s bl = *(const v8s*)&W1fl[fb];
      acc0[t] = __builtin_amdgcn_mfma_f32_16x16x32_bf16(a0h, bh, acc0[t], 0, 0, 0);
      acc0[t] = __builtin_amdgcn_mfma_f32_16x16x32_bf16(a0l, bh, acc0[t], 0, 0, 0);
      acc0[t] = __builtin_amdgcn_mfma_f32_16x16x32_bf16(a0h, bl, acc0[t], 0, 0, 0);
      acc1[t] = __builtin_amdgcn_mfma_f32_16x16x32_bf16(a1h, bh, acc1[t], 0, 0, 0);
      acc1[t] = __builtin_amdgcn_mfma_f32_16x16x32_bf16(a1l, bh, acc1[t], 0, 0, 0);
      acc1[t] = __builtin_amdgcn_mfma_f32_16x16x32_bf16(a1h, bl, acc1[t], 0, 0, 0);
    }
  }

  float p00 = 0.f, p01 = 0.f, p02 = 0.f, p03 = 0.f;
  float p10 = 0.f, p11 = 0.f, p12 = 0.f, p13 = 0.f;
  #pragma unroll
  for (int t = 0; t < 8; ++t) {
    float bb = b1[t * 16 + cq];
    float wg = W2v[t * 16 + cq];
    p00 = fmaf(silu_f(acc0[t][0] + bb), wg, p00);
    p01 = fmaf(silu_f(acc0[t][1] + bb), wg, p01);
    p02 = fmaf(silu_f(acc0[t][2] + bb), wg, p02);
    p03 = fmaf(silu_f(acc0[t][3] + bb), wg, p03);
    p10 = fmaf(silu_f(acc1[t][0] + bb), wg, p10);
    p11 = fmaf(silu_f(acc1[t][1] + bb), wg, p11);
    p12 = fmaf(silu_f(acc1[t][2] + bb), wg, p12);
    p13 = fmaf(silu_f(acc1[t][3] + bb), wg, p13);
  }
  #pragma unroll
  for (int off = 1; off < 16; off <<= 1) {
    p00 += __shfl_xor(p00, off); p01 += __shfl_xor(p01, off);
    p02 += __shfl_xor(p02, off); p03 += __shfl_xor(p03, off);
    p10 += __shfl_xor(p10, off); p11 += __shfl_xor(p11, off);
    p12 += __shfl_xor(p12, off); p13 += __shfl_xor(p13, off);
  }
  if (cq == 0) {
    gpre[0][w * 16 + q * 4 + 0] = p00;
    gpre[0][w * 16 + q * 4 + 1] = p01;
    gpre[0][w * 16 + q * 4 + 2] = p02;
    gpre[0][w * 16 + q * 4 + 3] = p03;
    gpre[1][w * 16 + q * 4 + 0] = p10;
    gpre[1][w * 16 + q * 4 + 1] = p11;
    gpre[1][w * 16 + q * 4 + 2] = p12;
    gpre[1][w * 16 + q * 4 + 3] = p13;
  }
  __syncthreads();

  if (tid < 128) {
    const int ee = tid >> 6, ll = tid & 63;
    float gv = sigmoid_f(gpre[ee][ll] + b2s[0]);
    gv *= y1cw[(b * 64 + ll) * 4 + 3];
    float t2 = gv;
    #pragma unroll
    for (int off = 32; off > 0; off >>= 1) t2 += __shfl_xor(t2, off);
    float inv = 1.0f / fmaxf(t2, 1e-8f);
    const int e = (ee == 0) ? e0 : e1;
    gate[(size_t)(b * 128 + e) * 64 + ll] = gv * inv;
  }
}

// ---------------------------------------------------------------------------
// K3b (new): parallel agg + inv-feats. grid=256: b=bid>>4, 8 energies/block.
// values[b] (40KB) staged once -> 10MB total L2 traffic; 1280 agg outputs /
// block over 256 threads (5 each, 64-fma serial over LDS).
// ---------------------------------------------------------------------------
__global__ void __launch_bounds__(256) k_agg(
    const float* __restrict__ gate, const float* __restrict__ values,
    float* __restrict__ inv_agg) {
  const int bid = blockIdx.x;
  const int b = bid >> 4;
  const int eg = bid & 15;
  const int tid = threadIdx.x;

  __shared__ float vS[10240];   // values[b]
  __shared__ float gS[8][64];   // 8 gate rows
  __shared__ float aS[8][160];  // agg

  {
    const float4* src = (const float4*)(values + (size_t)b * 10240);
    float4* dst = (float4*)vS;
    #pragma unroll
    for (int i = 0; i < 10; ++i) dst[tid + i * 256] = src[tid + i * 256];
    if (tid < 128)
      ((float4*)gS)[tid] =
          ((const float4*)(gate + ((size_t)b * 128 + eg * 8) * 64))[tid];
  }
  __syncthreads();

  #pragma unroll
  for (int it = 0; it < 5; ++it) {
    const int idx = it * 256 + tid;
    const int row = idx / 160;
    const int d = idx - row * 160;
    const float* gr = &gS[row][0];
    float a = 0.f;
    #pragma unroll 8
    for (int n = 0; n < 64; ++n) a = fmaf(gr[n], vS[n * 160 + d], a);
    aS[row][d] = a;
  }
  __syncthreads();

  for (int idx = tid; idx < 768; idx += 256) {
    const int row = idx / 96;
    const int ll = idx - row * 96;
    float rv;
    if (ll < 64) {
      rv = aS[row][ll];
    } else {
      const int o = ll - 64;
      float a0 = aS[row][64 + 3 * o + 0];
      float a1 = aS[row][64 + 3 * o + 1];
      float a2 = aS[row][64 + 3 * o + 2];
      rv = sqrtf((a0 * a0 + a1 * a1 + a2 * a2) * (1.0f / 3.0f) + 1e-8f);
    }
    inv_agg[((size_t)b * 128 + eg * 8 + row) * 96 + ll] = rv;
  }
}

// ---------------------------------------------------------------------------
// K4 v2 (reverted to R0): FUSED out-MLP (96->128 silu, 128->128 silu,
// 128->128) via MFMA. grid=128, 16 rows/block.
// ---------------------------------------------------------------------------
__global__ void __launch_bounds__(256) k_out(
    const float* __restrict__ X,
    const unsigned short* __restrict__ O0h, const unsigned short* __restrict__ O0l,
    const unsigned short* __restrict__ O1h, const unsigned short* __restrict__ O1l,
    const unsigned short* __restrict__ O2h, const unsigned short* __restrict__ O2l,
    const float* __restrict__ b0, const float* __restrict__ b1,
    const float* __restrict__ b2, float* __restrict__ out) {
  const int r0 = blockIdx.x * 16;
  const int tid = threadIdx.x;
  const int w = tid >> 6, l = tid & 63;
  const int q = l >> 4, cq = l & 15;
  const int t0 = 2 * w, t1 = 2 * w + 1;

  __shared__ float hS[16][132];

  v4f acc0 = (v4f){0.f, 0.f, 0.f, 0.f};
  v4f acc1 = (v4f){0.f, 0.f, 0.f, 0.f};
  {
    const float* xrow = X + (size_t)(r0 + cq) * 96 + q * 8;
    #pragma unroll
    for (int ks = 0; ks < 3; ++ks) {
      float4 p0 = *(const float4*)(xrow + ks * 32);
      float4 p1 = *(const float4*)(xrow + ks * 32 + 4);
      float xv[8] = {p0.x, p0.y, p0.z, p0.w, p1.x, p1.y, p1.z, p1.w};
      v8s avh, avl;
      #pragma unroll
      for (int j = 0; j < 8; ++j) {
        short hs, ls;
        split_trunc(xv[j], &hs, &ls);
        avh[j] = hs; avl[j] = ls;
      }
      v8s b0h = *(const v8s*)&O0h[((size_t)(ks * 8 + t0) * 64 + l) * 8];
      v8s b0l = *(const v8s*)&O0l[((size_t)(ks * 8 + t0) * 64 + l) * 8];
      v8s b1h = *(const v8s*)&O0h[((size_t)(ks * 8 + t1) * 64 + l) * 8];
      v8s b1l = *(const v8s*)&O0l[((size_t)(ks * 8 + t1) * 64 + l) * 8];
      acc0 = __builtin_amdgcn_mfma_f32_16x16x32_bf16(avh, b0h, acc0, 0, 0, 0);
      acc0 = __builtin_amdgcn_mfma_f32_16x16x32_bf16(avl, b0h, acc0, 0, 0, 0);
      acc0 = __builtin_amdgcn_mfma_f32_16x16x32_bf16(avh, b0l, acc0, 0, 0, 0);
      acc1 = __builtin_amdgcn_mfma_f32_16x16x32_bf16(avh, b1h, acc1, 0, 0, 0);
      acc1 = __builtin_amdgcn_mfma_f32_16x16x32_bf16(avl, b1h, acc1, 0, 0, 0);
      acc1 = __builtin_amdgcn_mfma_f32_16x16x32_bf16(avh, b1l, acc1, 0, 0, 0);
    }
  }
  {
    const float bb0 = b0[t0 * 16 + cq], bb1 = b0[t1 * 16 + cq];
    #pragma unroll
    for (int r = 0; r < 4; ++r) {
      hS[q * 4 + r][t0 * 16 + cq] = silu_f(acc0[r] + bb0);
      hS[q * 4 + r][t1 * 16 + cq] = silu_f(acc1[r] + bb1);
    }
  }
  __syncthreads();

  v8s a2h[4], a2l[4];
  #pragma unroll
  for (int ks = 0; ks < 4; ++ks) {
    float4 p0 = *(const float4*)&hS[cq][ks * 32 + q * 8];
    float4 p1 = *(const float4*)&hS[cq][ks * 32 + q * 8 + 4];
    float xv[8] = {p0.x, p0.y, p0.z, p0.w, p1.x, p1.y, p1.z, p1.w};
    #pragma unroll
    for (int j = 0; j < 8; ++j) {
      short hs, ls;
      split_trunc(xv[j], &hs, &ls);
      a2h[ks][j] = hs; a2l[ks][j] = ls;
    }
  }
  __syncthreads();
  acc0 = (v4f){0.f, 0.f, 0.f, 0.f};
  acc1 = (v4f){0.f, 0.f, 0.f, 0.f};
  #pragma unroll
  for (int ks = 0; ks < 4; ++ks) {
    v8s b0h = *(const v8s*)&O1h[((size_t)(ks * 8 + t0) * 64 + l) * 8];
    v8s b0l = *(const v8s*)&O1l[((size_t)(ks * 8 + t0) * 64 + l) * 8];
    v8s b1h = *(const v8s*)&O1h[((size_t)(ks * 8 + t1) * 64 + l) * 8];
    v8s b1l = *(const v8s*)&O1l[((size_t)(ks * 8 + t1) * 64 + l) * 8];
    acc0 = __builtin_amdgcn_mfma_f32_16x16x32_bf16(a2h[ks], b0h, acc0, 0, 0, 0);
    acc0 = __builtin_amdgcn_mfma_f32_16x16x32_bf16(a2l[ks], b0h, acc0, 0, 0, 0);
    acc0 = __builtin_amdgcn_mfma_f32_16x16x32_bf16(a2h[ks], b0l, acc0, 0, 0, 0);
    acc1 = __builtin_amdgcn_mfma_f32_16x16x32_bf16(a2h[ks], b1h, acc1, 0, 0, 0);
    acc1 = __builtin_amdgcn_mfma_f32_16x16x32_bf16(a2l[ks], b1h, acc1, 0, 0, 0);
    acc1 = __builtin_amdgcn_mfma_f32_16x16x32_bf16(a2h[ks], b1l, acc1, 0, 0, 0);
  }
  {
    const float bb0 = b1[t0 * 16 + cq], bb1 = b1[t1 * 16 + cq];
    #pragma unroll
    for (int r = 0; r < 4; ++r) {
      hS[q * 4 + r][t0 * 16 + cq] = silu_f(acc0[r] + bb0);
      hS[q * 4 + r][t1 * 16 + cq] = silu_f(acc1[r] + bb1);
    }
  }
  __syncthreads();

  #pragma unroll
  for (int ks = 0; ks < 4; ++ks) {
    float4 p0 = *(const float4*)&hS[cq][ks * 32 + q * 8];
    float4 p1 = *(const float4*)&hS[cq][ks * 32 + q * 8 + 4];
    float xv[8] = {p0.x, p0.y, p0.z, p0.w, p1.x, p1.y, p1.z, p1.w};
    #pragma unroll
    for (int j = 0; j < 8; ++j) {
      short hs, ls;
      split_trunc(xv[j], &hs, &ls);
      a2h[ks][j] = hs; a2l[ks][j] = ls;
    }
  }
  acc0 = (v4f){0.f, 0.f, 0.f, 0.f};
  acc1 = (v4f){0.f, 0.f, 0.f, 0.f};
  #pragma unroll
  for (int ks = 0; ks < 4; ++ks) {
    v8s b0h = *(const v8s*)&O2h[((size_t)(ks * 8 + t0) * 64 + l) * 8];
    v8s b0l = *(const v8s*)&O2l[((size_t)(ks * 8 + t0) * 64 + l) * 8];
    v8s b1h = *(const v8s*)&O2h[((size_t)(ks * 8 + t1) * 64 + l) * 8];
    v8s b1l = *(const v8s*)&O2l[((size_t)(ks * 8 + t1) * 64 + l) * 8];
    acc0 = __builtin_amdgcn_mfma_f32_16x16x32_bf16(a2h[ks], b0h, acc0, 0, 0, 0);
    acc0 = __builtin_amdgcn_mfma_f32_16x16x32_bf16(a2l[ks], b0h, acc0, 0, 0, 0);
    acc0 = __builtin_amdgcn_mfma_f32_16x16x32_bf16(a2h[ks], b0l, acc0, 0, 0, 0);
    acc1 = __builtin_amdgcn_mfma_f32_16x16x32_bf16(a2h[ks], b1h, acc1, 0, 0, 0);
    acc1 = __builtin_amdgcn_mfma_f32_16x16x32_bf16(a2l[ks], b1h, acc1, 0, 0, 0);
    acc1 = __builtin_amdgcn_mfma_f32_16x16x32_bf16(a2h[ks], b1l, acc1, 0, 0, 0);
  }
  {
    const float bb0 = b2[t0 * 16 + cq], bb1 = b2[t1 * 16 + cq];
    #pragma unroll
    for (int r = 0; r < 4; ++r) {
      out[(size_t)(r0 + q * 4 + r) * 128 + t0 * 16 + cq] = acc0[r] + bb0;
      out[(size_t)(r0 + q * 4 + r) * 128 + t1 * 16 + cq] = acc1[r] + bb1;
    }
  }
}

// ---------------------------------------------------------------------------
extern "C" void kernel_launch(void* const* d_in, const int* in_sizes, int n_in,
                              void* d_out, int out_size, void* d_ws, size_t ws_size,
                              hipStream_t stream) {
  const float* hf    = (const float*)d_in[0];
  const int*   z     = (const int*)  d_in[1];
  const float* pos   = (const float*)d_in[2];
  const float* e_feat= (const float*)d_in[4];
  const float* z_emb = (const float*)d_in[5];
  const float* vwW0  = (const float*)d_in[6];
  const float* vwb0  = (const float*)d_in[7];
  const float* vwW1  = (const float*)d_in[8];
  const float* vwb1  = (const float*)d_in[9];
  const float* vwW2  = (const float*)d_in[10];
  const float* vwb2  = (const float*)d_in[11];
  const float* scW0  = (const float*)d_in[12];
  const float* scb0  = (const float*)d_in[13];
  const float* scW1  = (const float*)d_in[14];
  const float* scb1  = (const float*)d_in[15];
  const float* scW2  = (const float*)d_in[16];
  const float* scb2  = (const float*)d_in[17];
  const float* oW0   = (const float*)d_in[18];
  const float* ob0   = (const float*)d_in[19];
  const float* oW1   = (const float*)d_in[20];
  const float* ob1   = (const float*)d_in[21];
  const float* oW2   = (const float*)d_in[22];
  const float* ob2   = (const float*)d_in[23];
  float* out = (float*)d_out;

  float* ws = (float*)d_ws;
  unsigned short* W2fh = (unsigned short*)(ws);            // 589824 fl
  unsigned short* W2fl = (unsigned short*)(ws + 589824);   // 589824 fl
  unsigned short* hTh  = (unsigned short*)(ws + 1179648);  // 65536 fl
  unsigned short* hTl  = (unsigned short*)(ws + 1245184);  // 65536 fl
  float* Pn     = ws + 1310720;   // 131072
  float* Pa     = Pn + 131072;    // 2048
  float* Pe     = Pa + 2048;      // 16384
  float* xvu    = Pe + 16384;     // 32768
  float* y1cw   = xvu + 32768;    // 4096
  float* values = y1cw + 4096;    // 163840
  float* gate   = values + 163840;// 131072 (region reserved 196608)
  unsigned short* W1fh = (unsigned short*)(gate + 196608);  // 8192 fl
  unsigned short* W1fl = (unsigned short*)(gate + 196608 + 8192);
  float* values8 = gate + 196608 + 16384;  // 8*163840 fl
  unsigned short* Ob = (unsigned short*)(values8 + 8 * 163840);
  unsigned short* O0h = Ob;
  unsigned short* O0l = Ob + 12288;
  unsigned short* O1h = Ob + 24576;
  unsigned short* O1l = Ob + 40960;
  unsigned short* O2h = Ob + 57344;
  unsigned short* O2l = Ob + 73728;
  float* invagg = (float*)(Ob + 90112);  // 196608 fl

  hipMemsetAsync(values8, 0, 8 * 163840 * sizeof(float), stream);

  k_front<<<1182, 256, 0, stream>>>(
      vwW2, W2fh, W2fl,
      hf, z, pos, z_emb, vwW0, vwb0, vwW1, vwb1, scW0,
      hTh, hTl, Pn, Pa, xvu, y1cw,
      scW1, W1fh, W1fl, oW0, oW1, oW2,
      O0h, O0l, O1h, O1l, O2h, O2l,
      e_feat, scb0, Pe);
  k_tp<<<1024, 256, 0, stream>>>(hTh, hTl, W2fh, W2fl, vwb2, hf, xvu,
                                 y1cw, values8);
  k_reduce<<<160, 256, 0, stream>>>(values8, values);
  k_gate<<<1024, 256, 0, stream>>>(Pa, Pe, Pn, W1fh, W1fl, scb1, scW2, scb2,
                                   y1cw, gate);
  k_agg<<<256, 256, 0, stream>>>(gate, values, invagg);
  k_out<<<128, 256, 0, stream>>>(invagg, O0h, O0l, O1h, O1l, O2h, O2l,
                                 ob0, ob1, ob2, out);
}

// Round 3
// 204.748 us; speedup vs baseline: 1.1275x; 1.1275x over previous
//
#include <hip/hip_runtime.h>
#include <hip/hip_bf16.h>
#include <math.h>

// Sizes: B=16, N=64, nE=128, H=128, LAT=128, NS=64, NV=32, INV=96, D_NODE=160
#define SQRT3F 1.7320508075688772f
#define ALPHAF 0.10206207261596577f  // 1/sqrt(96)
#define PIF 3.14159265358979323846f

typedef short v8s __attribute__((ext_vector_type(8)));
typedef float v4f __attribute__((ext_vector_type(4)));

__device__ __forceinline__ float silu_f(float x) {
  return x / (1.0f + __expf(-x));
}
__device__ __forceinline__ float sigmoid_f(float x) {
  return 1.0f / (1.0f + __expf(-x));
}
__device__ __forceinline__ unsigned short f2bf(float f) {
  unsigned int u = __float_as_uint(f);
  unsigned int r = (u + 0x7fffu + ((u >> 16) & 1u)) >> 16;
  return (unsigned short)r;
}
__device__ __forceinline__ float bf2f(unsigned short h) {
  return __uint_as_float(((unsigned int)h) << 16);
}
__device__ __forceinline__ void split_trunc(float x, short* h, short* l) {
  unsigned int u = __float_as_uint(x);
  unsigned short hs = (unsigned short)(u >> 16);
  float r = x - __uint_as_float((unsigned int)hs << 16);
  *h = (short)hs;
  *l = (short)(__float_as_uint(r) >> 16);
}

// async global->LDS, 16B per lane. Dest layout must be wave-uniform base +
// lane*16 (ours is base + tid*16 — exactly that). Guide §5 / m97.
__device__ __forceinline__ void async_lds16(const unsigned short* __restrict__ g,
                                            unsigned short* l) {
  __builtin_amdgcn_global_load_lds(
      (const __attribute__((address_space(1))) unsigned int*)g,
      (__attribute__((address_space(3))) unsigned int*)l, 16, 0, 0);
}

__device__ __forceinline__ void pack_frag(const float* __restrict__ W, int s0,
                                          unsigned short* __restrict__ fh,
                                          unsigned short* __restrict__ fl) {
  const int lane = s0 & 63;
  const int t = (s0 >> 6) & 7;
  const int ks = s0 >> 9;
  const int kbase = ks * 32 + (lane >> 4) * 8;
  const int n = t * 16 + (lane & 15);
  unsigned short hv[8], lv[8];
  #pragma unroll
  for (int j = 0; j < 8; ++j) {
    float w = W[(size_t)(kbase + j) * 128 + n];
    unsigned short h = f2bf(w);
    hv[j] = h;
    lv[j] = f2bf(w - bf2f(h));
  }
  *(uint4*)&fh[(size_t)s0 * 8] = *(uint4*)hv;
  *(uint4*)&fl[(size_t)s0 * 8] = *(uint4*)lv;
}

// ---------------------------------------------------------------------------
// K_FRONT: merged castw2 (blocks 0..575) + prep (576..1087, 2 nodes/block)
// + castw1/packout/Pe (1088..1181). (kept from R16 — saved ~10us)
// ---------------------------------------------------------------------------
__global__ void __launch_bounds__(256) k_front(
    const float* __restrict__ W2, unsigned short* __restrict__ W2fh,
    unsigned short* __restrict__ W2fl,
    const float* __restrict__ hf, const int* __restrict__ z,
    const float* __restrict__ pos, const float* __restrict__ z_emb,
    const float* __restrict__ vwW0, const float* __restrict__ vwb0,
    const float* __restrict__ vwW1, const float* __restrict__ vwb1,
    const float* __restrict__ scW0,
    unsigned short* __restrict__ hTh, unsigned short* __restrict__ hTl,
    float* __restrict__ Pn, float* __restrict__ Pa,
    float* __restrict__ xvu, float* __restrict__ y1cw,
    const float* __restrict__ scW1,
    unsigned short* __restrict__ W1fh, unsigned short* __restrict__ W1fl,
    const float* __restrict__ oW0, const float* __restrict__ oW1,
    const float* __restrict__ oW2,
    unsigned short* __restrict__ O0h, unsigned short* __restrict__ O0l,
    unsigned short* __restrict__ O1h, unsigned short* __restrict__ O1l,
    unsigned short* __restrict__ O2h, unsigned short* __restrict__ O2l,
    const float* __restrict__ e_feat, const float* __restrict__ scb0,
    float* __restrict__ Pe) {
  const int bid = blockIdx.x;
  const int tid = threadIdx.x;
  __shared__ float S[2304];

  if (bid < 576) {
    const int T = bid;
    float (*Tl)[17] = (float(*)[17])S;
    for (int idx = tid; idx < 2048; idx += 256) {
      int k = idx >> 4, cc = idx & 15;
      Tl[k][cc] = W2[(size_t)k * 9216 + T * 16 + cc];
    }
    __syncthreads();
    const int ks = tid >> 6, lane = tid & 63;
    const int q = lane >> 4, cq = lane & 15;
    const int k0 = ks * 32 + q * 8;
    unsigned short hv[8], lv[8];
    #pragma unroll
    for (int j = 0; j < 8; ++j) {
      float wv = Tl[k0 + j][cq];
      unsigned short h = f2bf(wv);
      hv[j] = h;
      lv[j] = f2bf(wv - bf2f(h));
    }
    size_t base = ((size_t)(T * 4 + ks) * 64 + lane) * 8;
    *(uint4*)&W2fh[base] = *(uint4*)hv;
    *(uint4*)&W2fl[base] = *(uint4*)lv;
  } else if (bid < 1088) {
    const int sb = tid >> 7;
    const int t = tid & 127;
    const int g = (bid - 576) * 2 + sb;
    const int b = g >> 6, n = g & 63;
    float* vin  = S + sb * 1152;
    float* invn = vin + 64;
    float* h0   = invn + 96;
    float* uS   = h0 + 128;
    float* rS   = uS + 3;

    if (t == 0) {
      float px = pos[g * 3 + 0] - pos[(b * 64) * 3 + 0];
      float py = pos[g * 3 + 1] - pos[(b * 64) * 3 + 1];
      float pz = pos[g * 3 + 2] - pos[(b * 64) * 3 + 2];
      float r = sqrtf(px * px + py * py + pz * pz + 1e-12f);
      float rm = fmaxf(r, 1e-8f);
      uS[0] = px / rm; uS[1] = py / rm; uS[2] = pz / rm;
      rS[0] = r;
    }
    __syncthreads();
    const float r = rS[0];

    if (t < 32) {
      const float delta = 6.0f / 31.0f;
      const float gamma = 1.0f / (delta * delta + 1e-12f);
      int zi = z[g];
      vin[t] = z_emb[zi * 32 + t];
      float rc = fminf(r, 6.0f);
      float d = rc - (float)t * delta;
      vin[32 + t] = __expf(-gamma * d * d);
      float a = hf[g * 160 + 64 + t * 3 + 0] * uS[0]
              + hf[g * 160 + 64 + t * 3 + 1] * uS[1]
              + hf[g * 160 + 64 + t * 3 + 2] * uS[2];
      xvu[g * 32 + t] = a;
    }
    if (t < 96) {
      if (t < 64) {
        invn[t] = hf[g * 160 + t];
      } else {
        int o = t - 64;
        float v0 = hf[g * 160 + 64 + o * 3 + 0];
        float v1 = hf[g * 160 + 64 + o * 3 + 1];
        float v2 = hf[g * 160 + 64 + o * 3 + 2];
        invn[t] = sqrtf((v0 * v0 + v1 * v1 + v2 * v2) * (1.0f / 3.0f) + 1e-8f);
      }
    }
    if (t == 0) {
      float cw = 0.0f;
      if (r <= 6.0f && n != 0) cw = 0.5f * (cosf(PIF * r * (1.0f / 6.0f)) + 1.0f);
      y1cw[g * 4 + 0] = SQRT3F * uS[0];
      y1cw[g * 4 + 1] = SQRT3F * uS[1];
      y1cw[g * 4 + 2] = SQRT3F * uS[2];
      y1cw[g * 4 + 3] = cw;
    }
    __syncthreads();

    {
      float a = vwb0[t];
      #pragma unroll 8
      for (int k = 0; k < 64; ++k) a = fmaf(vin[k], vwW0[k * 128 + t], a);
      h0[t] = silu_f(a);
    }
    __syncthreads();
    {
      float a = vwb1[t];
      #pragma unroll 8
      for (int k = 0; k < 128; ++k) a = fmaf(h0[k], vwW1[k * 128 + t], a);
      float hv = silu_f(a);
      unsigned short hh = f2bf(hv);
      hTh[(size_t)g * 128 + t] = hh;
      hTl[(size_t)g * 128 + t] = f2bf(hv - bf2f(hh));
    }
    {
      float p = 0.0f;
      #pragma unroll 8
      for (int k = 0; k < 96; ++k) p = fmaf(invn[k], scW0[(96 + k) * 128 + t], p);
      #pragma unroll 8
      for (int k = 0; k < 64; ++k) p = fmaf(vin[k], scW0[(192 + k) * 128 + t], p);
      Pn[(size_t)g * 128 + t] = p;
    }
    if (n == 0) {
      float p = 0.0f;
      #pragma unroll 8
      for (int k = 0; k < 96; ++k) p = fmaf(invn[k], scW0[k * 128 + t], p);
      Pa[b * 128 + t] = p;
    }
  } else {
    const int sb = bid - 1088;
    if (sb < 8) {
      pack_frag(scW1, sb * 256 + tid, W1fh, W1fl);
    } else if (sb < 30) {
      const int s = (sb - 8) * 256 + tid;
      if (s >= 5632) return;
      if (s < 1536)       pack_frag(oW0, s, O0h, O0l);
      else if (s < 3584)  pack_frag(oW1, s - 1536, O1h, O1l);
      else                pack_frag(oW2, s - 3584, O2h, O2l);
    } else {
      const int e = (sb - 30) * 2 + (tid >> 7);
      const int t = tid & 127;
      float a = scb0[t];
      #pragma unroll
      for (int k = 0; k < 16; ++k)
        a = fmaf(e_feat[e * 16 + k], scW0[(256 + k) * 128 + t], a);
      Pe[e * 128 + t] = a;
    }
  }
}

// ---------------------------------------------------------------------------
// K2 v14 = v12 (proven 41us: 18-tile chain, grid 512, LDS epilogue) with ONE
// change: staging via global_load_lds (async DMA, no VGPR round-trip, no
// ds_write). Dest Bst[buf][tid] = wave-uniform base + lane*16 — the exact
// layout the DMA requires. R2 post-mortem: chain-split + direct-register
// atomics collapsed occupancy to 9% (serialized atomic tail); reverted.
// ---------------------------------------------------------------------------
__device__ __forceinline__ int tile_of(int cs, int t) {
  if (t < 8)  return cs * 8 + t;
  if (t < 12) return 256 + cs * 4 + (t - 8);
  if (t < 14) return 384 + cs * 2 + (t - 12);
  return 448 + cs * 4 + (t - 14);
}

__global__ void __launch_bounds__(256) k_tp(
    const unsigned short* __restrict__ hTh, const unsigned short* __restrict__ hTl,
    const unsigned short* __restrict__ W2fh, const unsigned short* __restrict__ W2fl,
    const float* __restrict__ b2, const float* __restrict__ hf,
    const float* __restrict__ xvu, const float* __restrict__ y1cw,
    float* __restrict__ values8) {
  const int bid = blockIdx.x;
  const int cs = bid & 31;
  const int g0 = (bid >> 5) * 64;
  const int p8 = cs & 7;
  const int tid = threadIdx.x;
  const int w = tid >> 6, l = tid & 63;
  const int q = l >> 4, cq = l & 15;

  __shared__ unsigned short BstH[2][256][8];
  __shared__ unsigned short BstL[2][256][8];
  __shared__ float valsS[64][160];
  __shared__ float svS[64][32];

  const int anode = g0 + w * 16 + cq;
  v8s ah0 = *(const v8s*)&hTh[(size_t)anode * 128 + 0 * 32 + q * 8];
  v8s ah1 = *(const v8s*)&hTh[(size_t)anode * 128 + 1 * 32 + q * 8];
  v8s ah2 = *(const v8s*)&hTh[(size_t)anode * 128 + 2 * 32 + q * 8];
  v8s ah3 = *(const v8s*)&hTh[(size_t)anode * 128 + 3 * 32 + q * 8];
  v8s al0 = *(const v8s*)&hTl[(size_t)anode * 128 + 0 * 32 + q * 8];
  v8s al1 = *(const v8s*)&hTl[(size_t)anode * 128 + 1 * 32 + q * 8];
  v8s al2 = *(const v8s*)&hTl[(size_t)anode * 128 + 2 * 32 + q * 8];
  v8s al3 = *(const v8s*)&hTl[(size_t)anode * 128 + 3 * 32 + q * 8];

  float racc1[4][4] = {{0.f}};
  float racc2[2][4] = {{0.f}};
  float racc3[2][4][3] = {{{0.f}}};
  float racc4[4][4] = {{0.f}};

  const int nrow = w * 16 + q * 4;

  {
    const int T = tile_of(cs, 0);
    async_lds16(&W2fh[(size_t)T * 2048 + tid * 8], &BstH[0][tid][0]);
    async_lds16(&W2fl[(size_t)T * 2048 + tid * 8], &BstL[0][tid][0]);
  }
  __syncthreads();

  #pragma unroll
  for (int t = 0; t < 18; ++t) {
    const int buf = t & 1;
    if (t < 17) {
      const int Tn = tile_of(cs, t + 1);
      async_lds16(&W2fh[(size_t)Tn * 2048 + tid * 8], &BstH[buf ^ 1][tid][0]);
      async_lds16(&W2fl[(size_t)Tn * 2048 + tid * 8], &BstL[buf ^ 1][tid][0]);
    }

    const int T = tile_of(cs, t);
    v8s bh0 = *(const v8s*)&BstH[buf][0 * 64 + l][0];
    v8s bh1 = *(const v8s*)&BstH[buf][1 * 64 + l][0];
    v8s bh2 = *(const v8s*)&BstH[buf][2 * 64 + l][0];
    v8s bh3 = *(const v8s*)&BstH[buf][3 * 64 + l][0];
    v8s bl0 = *(const v8s*)&BstL[buf][0 * 64 + l][0];
    v8s bl1 = *(const v8s*)&BstL[buf][1 * 64 + l][0];
    v8s bl2 = *(const v8s*)&BstL[buf][2 * 64 + l][0];
    v8s bl3 = *(const v8s*)&BstL[buf][3 * 64 + l][0];

    v4f a0 = (v4f){0.f, 0.f, 0.f, 0.f};
    v4f a1 = (v4f){0.f, 0.f, 0.f, 0.f};
    v4f a2 = (v4f){0.f, 0.f, 0.f, 0.f};
    a0 = __builtin_amdgcn_mfma_f32_16x16x32_bf16(ah0, bh0, a0, 0, 0, 0);
    a1 = __builtin_amdgcn_mfma_f32_16x16x32_bf16(al0, bh0, a1, 0, 0, 0);
    a2 = __builtin_amdgcn_mfma_f32_16x16x32_bf16(ah0, bl0, a2, 0, 0, 0);
    a0 = __builtin_amdgcn_mfma_f32_16x16x32_bf16(ah1, bh1, a0, 0, 0, 0);
    a1 = __builtin_amdgcn_mfma_f32_16x16x32_bf16(al1, bh1, a1, 0, 0, 0);
    a2 = __builtin_amdgcn_mfma_f32_16x16x32_bf16(ah1, bl1, a2, 0, 0, 0);
    a0 = __builtin_amdgcn_mfma_f32_16x16x32_bf16(ah2, bh2, a0, 0, 0, 0);
    a1 = __builtin_amdgcn_mfma_f32_16x16x32_bf16(al2, bh2, a1, 0, 0, 0);
    a2 = __builtin_amdgcn_mfma_f32_16x16x32_bf16(ah2, bl2, a2, 0, 0, 0);
    a0 = __builtin_amdgcn_mfma_f32_16x16x32_bf16(ah3, bh3, a0, 0, 0, 0);
    a1 = __builtin_amdgcn_mfma_f32_16x16x32_bf16(al3, bh3, a1, 0, 0, 0);
    a2 = __builtin_amdgcn_mfma_f32_16x16x32_bf16(ah3, bl3, a2, 0, 0, 0);
    a0 += a1; a0 += a2;
    const float bj = b2[T * 16 + cq];
    v4f tp = a0;
    tp[0] += bj; tp[1] += bj; tp[2] += bj; tp[3] += bj;

    if (t < 8) {
      const int i = cs * 2 + (t >> 2);
      const int m = t & 3;
      #pragma unroll
      for (int r = 0; r < 4; ++r)
        racc1[m][r] = fmaf(hf[(size_t)(g0 + nrow + r) * 160 + i], tp[r], racc1[m][r]);
    } else if (t < 12) {
      const int i = cs * 2 + ((t - 8) >> 1);
      const int m = (t - 8) & 1;
      #pragma unroll
      for (int r = 0; r < 4; ++r)
        racc2[m][r] = fmaf(hf[(size_t)(g0 + nrow + r) * 160 + i], tp[r], racc2[m][r]);
    } else if (t < 14) {
      const int m = (t - 12) & 1;
      #pragma unroll
      for (int r = 0; r < 4; ++r) {
        const float* xvp = hf + (size_t)(g0 + nrow + r) * 160 + 64 + 3 * cs;
        #pragma unroll
        for (int cc = 0; cc < 3; ++cc)
          racc3[m][r][cc] = fmaf(xvp[cc], tp[r], racc3[m][r][cc]);
      }
    } else {
      const int m = (t - 14) & 3;
      #pragma unroll
      for (int r = 0; r < 4; ++r)
        racc4[m][r] = fmaf(xvu[(size_t)(g0 + nrow + r) * 32 + cs], tp[r], racc4[m][r]);
    }
    __syncthreads();
  }

  // epilogue: owner-exclusive plain stores
  #pragma unroll
  for (int r = 0; r < 4; ++r) {
    const int n = nrow + r;
    #pragma unroll
    for (int m = 0; m < 4; ++m)
      valsS[n][m * 16 + cq] = racc1[m][r] + racc4[m][r];
    #pragma unroll
    for (int m = 0; m < 2; ++m)
      svS[n][m * 16 + cq] = racc2[m][r];
    #pragma unroll
    for (int m = 0; m < 2; ++m)
      #pragma unroll
      for (int cc = 0; cc < 3; ++cc)
        valsS[n][64 + 3 * (m * 16 + cq) + cc] = racc3[m][r][cc];
  }
  __syncthreads();

  float* vtgt = values8 + (size_t)p8 * 163840;
  const float* y1b = y1cw + (size_t)g0 * 4;
  for (int idx = tid; idx < 10240; idx += 256) {
    int n = idx / 160, d = idx - n * 160;
    float v = valsS[n][d];
    if (d >= 64) {
      int dd = d - 64, o = dd / 3, cc = dd - 3 * o;
      v = fmaf(svS[n][o], y1b[n * 4 + cc], v);
    }
    atomicAdd(&vtgt[(size_t)(g0 + n) * 160 + d], v);
  }
}

// ---------------------------------------------------------------------------
// K2b: values[n][d] = ALPHAF * sum_p values8[p][n][d]. grid=160, block=256.
// ---------------------------------------------------------------------------
__global__ void __launch_bounds__(256) k_reduce(
    const float* __restrict__ values8, float* __restrict__ values) {
  const int s = blockIdx.x * 256 + threadIdx.x;
  float4 acc = make_float4(0.f, 0.f, 0.f, 0.f);
  #pragma unroll
  for (int p = 0; p < 8; ++p) {
    float4 v = *(const float4*)&values8[(size_t)p * 163840 + s * 4];
    acc.x += v.x; acc.y += v.y; acc.z += v.z; acc.w += v.w;
  }
  acc.x *= ALPHAF; acc.y *= ALPHAF; acc.z *= ALPHAF; acc.w *= ALPHAF;
  *(float4*)&values[(size_t)s * 4] = acc;
}

// ---------------------------------------------------------------------------
// K3 v6: MLP-only gate kernel (unchanged from R1). grid=1024, 2 energies/
// block. Norm folded into the gate write via butterfly shfl_xor.
// ---------------------------------------------------------------------------
__global__ void __launch_bounds__(256, 4) k_gate(
    const float* __restrict__ Pa, const float* __restrict__ Pe,
    const float* __restrict__ Pn,
    const unsigned short* __restrict__ W1fh, const unsigned short* __restrict__ W1fl,
    const float* __restrict__ b1, const float* __restrict__ W2v,
    const float* __restrict__ b2s, const float* __restrict__ y1cw,
    float* __restrict__ gate) {
  const int bid = blockIdx.x;
  const int b = bid >> 6;
  const int e0 = (bid & 63) * 2, e1 = e0 + 1;
  const int tid = threadIdx.x;

  __shared__ float Prow0[128], Prow1[128];
  __shared__ float gpre[2][64];

  if (tid < 128) {
    float pa = Pa[b * 128 + tid];
    Prow0[tid] = pa + Pe[e0 * 128 + tid];
    Prow1[tid] = pa + Pe[e1 * 128 + tid];
  }
  __syncthreads();

  const int w = tid >> 6, l = tid & 63;
  const int q = l >> 4, cq = l & 15;
  const int node = w * 16 + cq;
  const float* pnrow = Pn + (size_t)(b * 64 + node) * 128;

  v4f acc0[8], acc1[8];
  #pragma unroll
  for (int t = 0; t < 8; ++t) {
    acc0[t] = (v4f){0.f, 0.f, 0.f, 0.f};
    acc1[t] = (v4f){0.f, 0.f, 0.f, 0.f};
  }

  #pragma unroll
  for (int ks = 0; ks < 4; ++ks) {
    const int k0 = ks * 32 + q * 8;
    float4 p0 = *(const float4*)(pnrow + k0);
    float4 p1 = *(const float4*)(pnrow + k0 + 4);
    float pv[8] = {p0.x, p0.y, p0.z, p0.w, p1.x, p1.y, p1.z, p1.w};
    float4 r00 = *(const float4*)(&Prow0[k0]);
    float4 r01 = *(const float4*)(&Prow0[k0 + 4]);
    float4 r10 = *(const float4*)(&Prow1[k0]);
    float4 r11 = *(const float4*)(&Prow1[k0 + 4]);
    float rv0[8] = {r00.x, r00.y, r00.z, r00.w, r01.x, r01.y, r01.z, r01.w};
    float rv1[8] = {r10.x, r10.y, r10.z, r10.w, r11.x, r11.y, r11.z, r11.w};
    v8s a0h, a0l, a1h, a1l;
    #pragma unroll
    for (int j = 0; j < 8; ++j) {
      short hs, ls;
      split_trunc(silu_f(pv[j] + rv0[j]), &hs, &ls);
      a0h[j] = hs; a0l[j] = ls;
      split_trunc(silu_f(pv[j] + rv1[j]), &hs, &ls);
      a1h[j] = hs; a1l[j] = ls;
    }
    #pragma unroll
    for (int t = 0; t < 8; ++t) {
      const size_t fb = (size_t)((ks * 8 + t) * 64 + l) * 8;
      v8s bh = *(const v8s*)&W1fh[fb];
      v8s bl = *(const v8s*)&W1fl[fb];
      acc0[t] = __builtin_amdgcn_mfma_f32_16x16x32_bf16(a0h, bh, acc0[t], 0, 0, 0);
      acc0[t] = __builtin_amdgcn_mfma_f32_16x16x32_bf16(a0l, bh, acc0[t], 0, 0, 0);
      acc0[t] = __builtin_amdgcn_mfma_f32_16x16x32_bf16(a0h, bl, acc0[t], 0, 0, 0);
      acc1[t] = __builtin_amdgcn_mfma_f32_16x16x32_bf16(a1h, bh, acc1[t], 0, 0, 0);
      acc1[t] = __builtin_amdgcn_mfma_f32_16x16x32_bf16(a1l, bh, acc1[t], 0, 0, 0);
      acc1[t] = __builtin_amdgcn_mfma_f32_16x16x32_bf16(a1h, bl, acc1[t], 0, 0, 0);
    }
  }

  float p00 = 0.f, p01 = 0.f, p02 = 0.f, p03 = 0.f;
  float p10 = 0.f, p11 = 0.f, p12 = 0.f, p13 = 0.f;
  #pragma unroll
  for (int t = 0; t < 8; ++t) {
    float bb = b1[t * 16 + cq];
    float wg = W2v[t * 16 + cq];
    p00 = fmaf(silu_f(acc0[t][0] + bb), wg, p00);
    p01 = fmaf(silu_f(acc0[t][1] + bb), wg, p01);
    p02 = fmaf(silu_f(acc0[t][2] + bb), wg, p02);
    p03 = fmaf(silu_f(acc0[t][3] + bb), wg, p03);
    p10 = fmaf(silu_f(acc1[t][0] + bb), wg, p10);
    p11 = fmaf(silu_f(acc1[t][1] + bb), wg, p11);
    p12 = fmaf(silu_f(acc1[t][2] + bb), wg, p12);
    p13 = fmaf(silu_f(acc1[t][3] + bb), wg, p13);
  }
  #pragma unroll
  for (int off = 1; off < 16; off <<= 1) {
    p00 += __shfl_xor(p00, off); p01 += __shfl_xor(p01, off);
    p02 += __shfl_xor(p02, off); p03 += __shfl_xor(p03, off);
    p10 += __shfl_xor(p10, off); p11 += __shfl_xor(p11, off);
    p12 += __shfl_xor(p12, off); p13 += __shfl_xor(p13, off);
  }
  if (cq == 0) {
    gpre[0][w * 16 + q * 4 + 0] = p00;
    gpre[0][w * 16 + q * 4 + 1] = p01;
    gpre[0][w * 16 + q * 4 + 2] = p02;
    gpre[0][w * 16 + q * 4 + 3] = p03;
    gpre[1][w * 16 + q * 4 + 0] = p10;
    gpre[1][w * 16 + q * 4 + 1] = p11;
    gpre[1][w * 16 + q * 4 + 2] = p12;
    gpre[1][w * 16 + q * 4 + 3] = p13;
  }
  __syncthreads();

  if (tid < 128) {
    const int ee = tid >> 6, ll = tid & 63;
    float gv = sigmoid_f(gpre[ee][ll] + b2s[0]);
    gv *= y1cw[(b * 64 + ll) * 4 + 3];
    float t2 = gv;
    #pragma unroll
    for (int off = 32; off > 0; off >>= 1) t2 += __shfl_xor(t2, off);
    float inv = 1.0f / fmaxf(t2, 1e-8f);
    const int e = (ee == 0) ? e0 : e1;
    gate[(size_t)(b * 128 + e) * 64 + ll] = gv * inv;
  }
}

// ---------------------------------------------------------------------------
// K3b: parallel agg + inv-feats (unchanged from R2). grid=256: b=bid>>4,
// 8 energies/block. values[b] (40KB) staged once -> 10MB total L2 traffic.
// ---------------------------------------------------------------------------
__global__ void __launch_bounds__(256) k_agg(
    const float* __restrict__ gate, const float* __restrict__ values,
    float* __restrict__ inv_agg) {
  const int bid = blockIdx.x;
  const int b = bid >> 4;
  const int eg = bid & 15;
  const int tid = threadIdx.x;

  __shared__ float vS[10240];   // values[b]
  __shared__ float gS[8][64];   // 8 gate rows
  __shared__ float aS[8][160];  // agg

  {
    const float4* src = (const float4*)(values + (size_t)b * 10240);
    float4* dst = (float4*)vS;
    #pragma unroll
    for (int i = 0; i < 10; ++i) dst[tid + i * 256] = src[tid + i * 256];
    if (tid < 128)
      ((float4*)gS)[tid] =
          ((const float4*)(gate + ((size_t)b * 128 + eg * 8) * 64))[tid];
  }
  __syncthreads();

  #pragma unroll
  for (int it = 0; it < 5; ++it) {
    const int idx = it * 256 + tid;
    const int row = idx / 160;
    const int d = idx - row * 160;
    const float* gr = &gS[row][0];
    float a = 0.f;
    #pragma unroll 8
    for (int n = 0; n < 64; ++n) a = fmaf(gr[n], vS[n * 160 + d], a);
    aS[row][d] = a;
  }
  __syncthreads();

  for (int idx = tid; idx < 768; idx += 256) {
    const int row = idx / 96;
    const int ll = idx - row * 96;
    float rv;
    if (ll < 64) {
      rv = aS[row][ll];
    } else {
      const int o = ll - 64;
      float a0 = aS[row][64 + 3 * o + 0];
      float a1 = aS[row][64 + 3 * o + 1];
      float a2 = aS[row][64 + 3 * o + 2];
      rv = sqrtf((a0 * a0 + a1 * a1 + a2 * a2) * (1.0f / 3.0f) + 1e-8f);
    }
    inv_agg[((size_t)b * 128 + eg * 8 + row) * 96 + ll] = rv;
  }
}

// ---------------------------------------------------------------------------
// K4 v2: FUSED out-MLP (96->128 silu, 128->128 silu, 128->128) via MFMA.
// grid=128, 16 rows/block.
// ---------------------------------------------------------------------------
__global__ void __launch_bounds__(256) k_out(
    const float* __restrict__ X,
    const unsigned short* __restrict__ O0h, const unsigned short* __restrict__ O0l,
    const unsigned short* __restrict__ O1h, const unsigned short* __restrict__ O1l,
    const unsigned short* __restrict__ O2h, const unsigned short* __restrict__ O2l,
    const float* __restrict__ b0, const float* __restrict__ b1,
    const float* __restrict__ b2, float* __restrict__ out) {
  const int r0 = blockIdx.x * 16;
  const int tid = threadIdx.x;
  const int w = tid >> 6, l = tid & 63;
  const int q = l >> 4, cq = l & 15;
  const int t0 = 2 * w, t1 = 2 * w + 1;

  __shared__ float hS[16][132];

  v4f acc0 = (v4f){0.f, 0.f, 0.f, 0.f};
  v4f acc1 = (v4f){0.f, 0.f, 0.f, 0.f};
  {
    const float* xrow = X + (size_t)(r0 + cq) * 96 + q * 8;
    #pragma unroll
    for (int ks = 0; ks < 3; ++ks) {
      float4 p0 = *(const float4*)(xrow + ks * 32);
      float4 p1 = *(const float4*)(xrow + ks * 32 + 4);
      float xv[8] = {p0.x, p0.y, p0.z, p0.w, p1.x, p1.y, p1.z, p1.w};
      v8s avh, avl;
      #pragma unroll
      for (int j = 0; j < 8; ++j) {
        short hs, ls;
        split_trunc(xv[j], &hs, &ls);
        avh[j] = hs; avl[j] = ls;
      }
      v8s b0h = *(const v8s*)&O0h[((size_t)(ks * 8 + t0) * 64 + l) * 8];
      v8s b0l = *(const v8s*)&O0l[((size_t)(ks * 8 + t0) * 64 + l) * 8];
      v8s b1h = *(const v8s*)&O0h[((size_t)(ks * 8 + t1) * 64 + l) * 8];
      v8s b1l = *(const v8s*)&O0l[((size_t)(ks * 8 + t1) * 64 + l) * 8];
      acc0 = __builtin_amdgcn_mfma_f32_16x16x32_bf16(avh, b0h, acc0, 0, 0, 0);
      acc0 = __builtin_amdgcn_mfma_f32_16x16x32_bf16(avl, b0h, acc0, 0, 0, 0);
      acc0 = __builtin_amdgcn_mfma_f32_16x16x32_bf16(avh, b0l, acc0, 0, 0, 0);
      acc1 = __builtin_amdgcn_mfma_f32_16x16x32_bf16(avh, b1h, acc1, 0, 0, 0);
      acc1 = __builtin_amdgcn_mfma_f32_16x16x32_bf16(avl, b1h, acc1, 0, 0, 0);
      acc1 = __builtin_amdgcn_mfma_f32_16x16x32_bf16(avh, b1l, acc1, 0, 0, 0);
    }
  }
  {
    const float bb0 = b0[t0 * 16 + cq], bb1 = b0[t1 * 16 + cq];
    #pragma unroll
    for (int r = 0; r < 4; ++r) {
      hS[q * 4 + r][t0 * 16 + cq] = silu_f(acc0[r] + bb0);
      hS[q * 4 + r][t1 * 16 + cq] = silu_f(acc1[r] + bb1);
    }
  }
  __syncthreads();

  v8s a2h[4], a2l[4];
  #pragma unroll
  for (int ks = 0; ks < 4; ++ks) {
    float4 p0 = *(const float4*)&hS[cq][ks * 32 + q * 8];
    float4 p1 = *(const float4*)&hS[cq][ks * 32 + q * 8 + 4];
    float xv[8] = {p0.x, p0.y, p0.z, p0.w, p1.x, p1.y, p1.z, p1.w};
    #pragma unroll
    for (int j = 0; j < 8; ++j) {
      short hs, ls;
      split_trunc(xv[j], &hs, &ls);
      a2h[ks][j] = hs; a2l[ks][j] = ls;
    }
  }
  __syncthreads();
  acc0 = (v4f){0.f, 0.f, 0.f, 0.f};
  acc1 = (v4f){0.f, 0.f, 0.f, 0.f};
  #pragma unroll
  for (int ks = 0; ks < 4; ++ks) {
    v8s b0h = *(const v8s*)&O1h[((size_t)(ks * 8 + t0) * 64 + l) * 8];
    v8s b0l = *(const v8s*)&O1l[((size_t)(ks * 8 + t0) * 64 + l) * 8];
    v8s b1h = *(const v8s*)&O1h[((size_t)(ks * 8 + t1) * 64 + l) * 8];
    v8s b1l = *(const v8s*)&O1l[((size_t)(ks * 8 + t1) * 64 + l) * 8];
    acc0 = __builtin_amdgcn_mfma_f32_16x16x32_bf16(a2h[ks], b0h, acc0, 0, 0, 0);
    acc0 = __builtin_amdgcn_mfma_f32_16x16x32_bf16(a2l[ks], b0h, acc0, 0, 0, 0);
    acc0 = __builtin_amdgcn_mfma_f32_16x16x32_bf16(a2h[ks], b0l, acc0, 0, 0, 0);
    acc1 = __builtin_amdgcn_mfma_f32_16x16x32_bf16(a2h[ks], b1h, acc1, 0, 0, 0);
    acc1 = __builtin_amdgcn_mfma_f32_16x16x32_bf16(a2l[ks], b1h, acc1, 0, 0, 0);
    acc1 = __builtin_amdgcn_mfma_f32_16x16x32_bf16(a2h[ks], b1l, acc1, 0, 0, 0);
  }
  {
    const float bb0 = b1[t0 * 16 + cq], bb1 = b1[t1 * 16 + cq];
    #pragma unroll
    for (int r = 0; r < 4; ++r) {
      hS[q * 4 + r][t0 * 16 + cq] = silu_f(acc0[r] + bb0);
      hS[q * 4 + r][t1 * 16 + cq] = silu_f(acc1[r] + bb1);
    }
  }
  __syncthreads();

  #pragma unroll
  for (int ks = 0; ks < 4; ++ks) {
    float4 p0 = *(const float4*)&hS[cq][ks * 32 + q * 8];
    float4 p1 = *(const float4*)&hS[cq][ks * 32 + q * 8 + 4];
    float xv[8] = {p0.x, p0.y, p0.z, p0.w, p1.x, p1.y, p1.z, p1.w};
    #pragma unroll
    for (int j = 0; j < 8; ++j) {
      short hs, ls;
      split_trunc(xv[j], &hs, &ls);
      a2h[ks][j] = hs; a2l[ks][j] = ls;
    }
  }
  acc0 = (v4f){0.f, 0.f, 0.f, 0.f};
  acc1 = (v4f){0.f, 0.f, 0.f, 0.f};
  #pragma unroll
  for (int ks = 0; ks < 4; ++ks) {
    v8s b0h = *(const v8s*)&O2h[((size_t)(ks * 8 + t0) * 64 + l) * 8];
    v8s b0l = *(const v8s*)&O2l[((size_t)(ks * 8 + t0) * 64 + l) * 8];
    v8s b1h = *(const v8s*)&O2h[((size_t)(ks * 8 + t1) * 64 + l) * 8];
    v8s b1l = *(const v8s*)&O2l[((size_t)(ks * 8 + t1) * 64 + l) * 8];
    acc0 = __builtin_amdgcn_mfma_f32_16x16x32_bf16(a2h[ks], b0h, acc0, 0, 0, 0);
    acc0 = __builtin_amdgcn_mfma_f32_16x16x32_bf16(a2l[ks], b0h, acc0, 0, 0, 0);
    acc0 = __builtin_amdgcn_mfma_f32_16x16x32_bf16(a2h[ks], b0l, acc0, 0, 0, 0);
    acc1 = __builtin_amdgcn_mfma_f32_16x16x32_bf16(a2h[ks], b1h, acc1, 0, 0, 0);
    acc1 = __builtin_amdgcn_mfma_f32_16x16x32_bf16(a2l[ks], b1h, acc1, 0, 0, 0);
    acc1 = __builtin_amdgcn_mfma_f32_16x16x32_bf16(a2h[ks], b1l, acc1, 0, 0, 0);
  }
  {
    const float bb0 = b2[t0 * 16 + cq], bb1 = b2[t1 * 16 + cq];
    #pragma unroll
    for (int r = 0; r < 4; ++r) {
      out[(size_t)(r0 + q * 4 + r) * 128 + t0 * 16 + cq] = acc0[r] + bb0;
      out[(size_t)(r0 + q * 4 + r) * 128 + t1 * 16 + cq] = acc1[r] + bb1;
    }
  }
}

// ---------------------------------------------------------------------------
extern "C" void kernel_launch(void* const* d_in, const int* in_sizes, int n_in,
                              void* d_out, int out_size, void* d_ws, size_t ws_size,
                              hipStream_t stream) {
  const float* hf    = (const float*)d_in[0];
  const int*   z     = (const int*)  d_in[1];
  const float* pos   = (const float*)d_in[2];
  const float* e_feat= (const float*)d_in[4];
  const float* z_emb = (const float*)d_in[5];
  const float* vwW0  = (const float*)d_in[6];
  const float* vwb0  = (const float*)d_in[7];
  const float* vwW1  = (const float*)d_in[8];
  const float* vwb1  = (const float*)d_in[9];
  const float* vwW2  = (const float*)d_in[10];
  const float* vwb2  = (const float*)d_in[11];
  const float* scW0  = (const float*)d_in[12];
  const float* scb0  = (const float*)d_in[13];
  const float* scW1  = (const float*)d_in[14];
  const float* scb1  = (const float*)d_in[15];
  const float* scW2  = (const float*)d_in[16];
  const float* scb2  = (const float*)d_in[17];
  const float* oW0   = (const float*)d_in[18];
  const float* ob0   = (const float*)d_in[19];
  const float* oW1   = (const float*)d_in[20];
  const float* ob1   = (const float*)d_in[21];
  const float* oW2   = (const float*)d_in[22];
  const float* ob2   = (const float*)d_in[23];
  float* out = (float*)d_out;

  float* ws = (float*)d_ws;
  unsigned short* W2fh = (unsigned short*)(ws);            // 589824 fl
  unsigned short* W2fl = (unsigned short*)(ws + 589824);   // 589824 fl
  unsigned short* hTh  = (unsigned short*)(ws + 1179648);  // 65536 fl
  unsigned short* hTl  = (unsigned short*)(ws + 1245184);  // 65536 fl
  float* Pn     = ws + 1310720;   // 131072
  float* Pa     = Pn + 131072;    // 2048
  float* Pe     = Pa + 2048;      // 16384
  float* xvu    = Pe + 16384;     // 32768
  float* y1cw   = xvu + 32768;    // 4096
  float* values = y1cw + 4096;    // 163840
  float* gate   = values + 163840;// 131072 (region reserved 196608)
  unsigned short* W1fh = (unsigned short*)(gate + 196608);  // 8192 fl
  unsigned short* W1fl = (unsigned short*)(gate + 196608 + 8192);
  float* values8 = gate + 196608 + 16384;  // 8*163840 fl
  unsigned short* Ob = (unsigned short*)(values8 + 8 * 163840);
  unsigned short* O0h = Ob;
  unsigned short* O0l = Ob + 12288;
  unsigned short* O1h = Ob + 24576;
  unsigned short* O1l = Ob + 40960;
  unsigned short* O2h = Ob + 57344;
  unsigned short* O2l = Ob + 73728;
  float* invagg = (float*)(Ob + 90112);  // 196608 fl

  hipMemsetAsync(values8, 0, 8 * 163840 * sizeof(float), stream);

  k_front<<<1182, 256, 0, stream>>>(
      vwW2, W2fh, W2fl,
      hf, z, pos, z_emb, vwW0, vwb0, vwW1, vwb1, scW0,
      hTh, hTl, Pn, Pa, xvu, y1cw,
      scW1, W1fh, W1fl, oW0, oW1, oW2,
      O0h, O0l, O1h, O1l, O2h, O2l,
      e_feat, scb0, Pe);
  k_tp<<<512, 256, 0, stream>>>(hTh, hTl, W2fh, W2fl, vwb2, hf, xvu,
                                y1cw, values8);
  k_reduce<<<160, 256, 0, stream>>>(values8, values);
  k_gate<<<1024, 256, 0, stream>>>(Pa, Pe, Pn, W1fh, W1fl, scb1, scW2, scb2,
                                   y1cw, gate);
  k_agg<<<256, 256, 0, stream>>>(gate, values, invagg);
  k_out<<<128, 256, 0, stream>>>(invagg, O0h, O0l, O1h, O1l, O2h, O2l,
                                 ob0, ob1, ob2, out);
}

// Round 4
// 185.259 us; speedup vs baseline: 1.2461x; 1.1052x over previous
//
#include <hip/hip_runtime.h>
#include <hip/hip_bf16.h>
#include <math.h>

// Sizes: B=16, N=64, nE=128, H=128, LAT=128, NS=64, NV=32, INV=96, D_NODE=160
#define SQRT3F 1.7320508075688772f
#define ALPHAF 0.10206207261596577f  // 1/sqrt(96)
#define PIF 3.14159265358979323846f

typedef short v8s __attribute__((ext_vector_type(8)));
typedef float v4f __attribute__((ext_vector_type(4)));

__device__ __forceinline__ float silu_f(float x) {
  return x / (1.0f + __expf(-x));
}
__device__ __forceinline__ float sigmoid_f(float x) {
  return 1.0f / (1.0f + __expf(-x));
}
__device__ __forceinline__ unsigned short f2bf(float f) {
  unsigned int u = __float_as_uint(f);
  unsigned int r = (u + 0x7fffu + ((u >> 16) & 1u)) >> 16;
  return (unsigned short)r;
}
__device__ __forceinline__ float bf2f(unsigned short h) {
  return __uint_as_float(((unsigned int)h) << 16);
}
__device__ __forceinline__ void split_trunc(float x, short* h, short* l) {
  unsigned int u = __float_as_uint(x);
  unsigned short hs = (unsigned short)(u >> 16);
  float r = x - __uint_as_float((unsigned int)hs << 16);
  *h = (short)hs;
  *l = (short)(__float_as_uint(r) >> 16);
}

// async global->LDS, 16B per lane. Dest layout must be wave-uniform base +
// lane*16 (ours is base + tid*16 — exactly that). Guide §5 / m97.
__device__ __forceinline__ void async_lds16(const unsigned short* __restrict__ g,
                                            unsigned short* l) {
  __builtin_amdgcn_global_load_lds(
      (const __attribute__((address_space(1))) unsigned int*)g,
      (__attribute__((address_space(3))) unsigned int*)l, 16, 0, 0);
}

__device__ __forceinline__ void pack_frag(const float* __restrict__ W, int s0,
                                          unsigned short* __restrict__ fh,
                                          unsigned short* __restrict__ fl) {
  const int lane = s0 & 63;
  const int t = (s0 >> 6) & 7;
  const int ks = s0 >> 9;
  const int kbase = ks * 32 + (lane >> 4) * 8;
  const int n = t * 16 + (lane & 15);
  unsigned short hv[8], lv[8];
  #pragma unroll
  for (int j = 0; j < 8; ++j) {
    float w = W[(size_t)(kbase + j) * 128 + n];
    unsigned short h = f2bf(w);
    hv[j] = h;
    lv[j] = f2bf(w - bf2f(h));
  }
  *(uint4*)&fh[(size_t)s0 * 8] = *(uint4*)hv;
  *(uint4*)&fl[(size_t)s0 * 8] = *(uint4*)lv;
}

// ---------------------------------------------------------------------------
// K_FRONT: merged castw2 (blocks 0..575) + prep (576..1087, 2 nodes/block)
// + castw1/packout/Pe (1088..1181). (kept from R16 — saved ~10us)
// ---------------------------------------------------------------------------
__global__ void __launch_bounds__(256) k_front(
    const float* __restrict__ W2, unsigned short* __restrict__ W2fh,
    unsigned short* __restrict__ W2fl,
    const float* __restrict__ hf, const int* __restrict__ z,
    const float* __restrict__ pos, const float* __restrict__ z_emb,
    const float* __restrict__ vwW0, const float* __restrict__ vwb0,
    const float* __restrict__ vwW1, const float* __restrict__ vwb1,
    const float* __restrict__ scW0,
    unsigned short* __restrict__ hTh, unsigned short* __restrict__ hTl,
    float* __restrict__ Pn, float* __restrict__ Pa,
    float* __restrict__ xvu, float* __restrict__ y1cw,
    const float* __restrict__ scW1,
    unsigned short* __restrict__ W1fh, unsigned short* __restrict__ W1fl,
    const float* __restrict__ oW0, const float* __restrict__ oW1,
    const float* __restrict__ oW2,
    unsigned short* __restrict__ O0h, unsigned short* __restrict__ O0l,
    unsigned short* __restrict__ O1h, unsigned short* __restrict__ O1l,
    unsigned short* __restrict__ O2h, unsigned short* __restrict__ O2l,
    const float* __restrict__ e_feat, const float* __restrict__ scb0,
    float* __restrict__ Pe) {
  const int bid = blockIdx.x;
  const int tid = threadIdx.x;
  __shared__ float S[2304];

  if (bid < 576) {
    const int T = bid;
    float (*Tl)[17] = (float(*)[17])S;
    for (int idx = tid; idx < 2048; idx += 256) {
      int k = idx >> 4, cc = idx & 15;
      Tl[k][cc] = W2[(size_t)k * 9216 + T * 16 + cc];
    }
    __syncthreads();
    const int ks = tid >> 6, lane = tid & 63;
    const int q = lane >> 4, cq = lane & 15;
    const int k0 = ks * 32 + q * 8;
    unsigned short hv[8], lv[8];
    #pragma unroll
    for (int j = 0; j < 8; ++j) {
      float wv = Tl[k0 + j][cq];
      unsigned short h = f2bf(wv);
      hv[j] = h;
      lv[j] = f2bf(wv - bf2f(h));
    }
    size_t base = ((size_t)(T * 4 + ks) * 64 + lane) * 8;
    *(uint4*)&W2fh[base] = *(uint4*)hv;
    *(uint4*)&W2fl[base] = *(uint4*)lv;
  } else if (bid < 1088) {
    const int sb = tid >> 7;
    const int t = tid & 127;
    const int g = (bid - 576) * 2 + sb;
    const int b = g >> 6, n = g & 63;
    float* vin  = S + sb * 1152;
    float* invn = vin + 64;
    float* h0   = invn + 96;
    float* uS   = h0 + 128;
    float* rS   = uS + 3;

    if (t == 0) {
      float px = pos[g * 3 + 0] - pos[(b * 64) * 3 + 0];
      float py = pos[g * 3 + 1] - pos[(b * 64) * 3 + 1];
      float pz = pos[g * 3 + 2] - pos[(b * 64) * 3 + 2];
      float r = sqrtf(px * px + py * py + pz * pz + 1e-12f);
      float rm = fmaxf(r, 1e-8f);
      uS[0] = px / rm; uS[1] = py / rm; uS[2] = pz / rm;
      rS[0] = r;
    }
    __syncthreads();
    const float r = rS[0];

    if (t < 32) {
      const float delta = 6.0f / 31.0f;
      const float gamma = 1.0f / (delta * delta + 1e-12f);
      int zi = z[g];
      vin[t] = z_emb[zi * 32 + t];
      float rc = fminf(r, 6.0f);
      float d = rc - (float)t * delta;
      vin[32 + t] = __expf(-gamma * d * d);
      float a = hf[g * 160 + 64 + t * 3 + 0] * uS[0]
              + hf[g * 160 + 64 + t * 3 + 1] * uS[1]
              + hf[g * 160 + 64 + t * 3 + 2] * uS[2];
      xvu[g * 32 + t] = a;
    }
    if (t < 96) {
      if (t < 64) {
        invn[t] = hf[g * 160 + t];
      } else {
        int o = t - 64;
        float v0 = hf[g * 160 + 64 + o * 3 + 0];
        float v1 = hf[g * 160 + 64 + o * 3 + 1];
        float v2 = hf[g * 160 + 64 + o * 3 + 2];
        invn[t] = sqrtf((v0 * v0 + v1 * v1 + v2 * v2) * (1.0f / 3.0f) + 1e-8f);
      }
    }
    if (t == 0) {
      float cw = 0.0f;
      if (r <= 6.0f && n != 0) cw = 0.5f * (cosf(PIF * r * (1.0f / 6.0f)) + 1.0f);
      y1cw[g * 4 + 0] = SQRT3F * uS[0];
      y1cw[g * 4 + 1] = SQRT3F * uS[1];
      y1cw[g * 4 + 2] = SQRT3F * uS[2];
      y1cw[g * 4 + 3] = cw;
    }
    __syncthreads();

    {
      float a = vwb0[t];
      #pragma unroll 8
      for (int k = 0; k < 64; ++k) a = fmaf(vin[k], vwW0[k * 128 + t], a);
      h0[t] = silu_f(a);
    }
    __syncthreads();
    {
      float a = vwb1[t];
      #pragma unroll 8
      for (int k = 0; k < 128; ++k) a = fmaf(h0[k], vwW1[k * 128 + t], a);
      float hv = silu_f(a);
      unsigned short hh = f2bf(hv);
      hTh[(size_t)g * 128 + t] = hh;
      hTl[(size_t)g * 128 + t] = f2bf(hv - bf2f(hh));
    }
    {
      float p = 0.0f;
      #pragma unroll 8
      for (int k = 0; k < 96; ++k) p = fmaf(invn[k], scW0[(96 + k) * 128 + t], p);
      #pragma unroll 8
      for (int k = 0; k < 64; ++k) p = fmaf(vin[k], scW0[(192 + k) * 128 + t], p);
      Pn[(size_t)g * 128 + t] = p;
    }
    if (n == 0) {
      float p = 0.0f;
      #pragma unroll 8
      for (int k = 0; k < 96; ++k) p = fmaf(invn[k], scW0[k * 128 + t], p);
      Pa[b * 128 + t] = p;
    }
  } else {
    const int sb = bid - 1088;
    if (sb < 8) {
      pack_frag(scW1, sb * 256 + tid, W1fh, W1fl);
    } else if (sb < 30) {
      const int s = (sb - 8) * 256 + tid;
      if (s >= 5632) return;
      if (s < 1536)       pack_frag(oW0, s, O0h, O0l);
      else if (s < 3584)  pack_frag(oW1, s - 1536, O1h, O1l);
      else                pack_frag(oW2, s - 3584, O2h, O2l);
    } else {
      const int e = (sb - 30) * 2 + (tid >> 7);
      const int t = tid & 127;
      float a = scb0[t];
      #pragma unroll
      for (int k = 0; k < 16; ++k)
        a = fmaf(e_feat[e * 16 + k], scW0[(256 + k) * 128 + t], a);
      Pe[e * 128 + t] = a;
    }
  }
}

// ---------------------------------------------------------------------------
// K_MID = k_tp (v14, proven) + k_gate (v6, proven) MERGED into one launch.
// Both depend only on k_front and are mutually independent — merging removes
// a full device-drain boundary and co-schedules tp's stall-heavy barrier
// chain with gate's MFMA-dense blocks on the same CUs (m114: overlap ~ max).
// Role interleave: bid%3==0 -> tp (512 blocks), else gate (1024 blocks), so
// the initial dispatch wave already mixes roles on every CU. tp's p8
// partition stays XCD-pinned (tp_idx&7 <-> (3k)&7 is a fixed permutation).
// LDS union 56KB (svS folded into registers: the owner thread of racc3 also
// owns racc2, so sv*y1 is folded before the LDS store) -> 2 blocks/CU.
// ---------------------------------------------------------------------------
__device__ __forceinline__ int tile_of(int cs, int t) {
  if (t < 8)  return cs * 8 + t;
  if (t < 12) return 256 + cs * 4 + (t - 8);
  if (t < 14) return 384 + cs * 2 + (t - 12);
  return 448 + cs * 4 + (t - 14);
}

__device__ void tp_path(
    float* __restrict__ SH,
    const unsigned short* __restrict__ hTh, const unsigned short* __restrict__ hTl,
    const unsigned short* __restrict__ W2fh, const unsigned short* __restrict__ W2fl,
    const float* __restrict__ b2, const float* __restrict__ hf,
    const float* __restrict__ xvu, const float* __restrict__ y1cw,
    float* __restrict__ values8, int tp_idx) {
  const int cs = tp_idx & 31;
  const int g0 = (tp_idx >> 5) * 64;
  const int p8 = tp_idx & 7;
  const int tid = threadIdx.x;
  const int w = tid >> 6, l = tid & 63;
  const int q = l >> 4, cq = l & 15;

  unsigned short (*BstH)[256][8] = (unsigned short(*)[256][8])SH;         // 8KB
  unsigned short (*BstL)[256][8] = (unsigned short(*)[256][8])(SH + 2048); // 8KB
  float (*valsS)[160] = (float(*)[160])(SH + 4096);                        // 40KB

  const int anode = g0 + w * 16 + cq;
  v8s ah0 = *(const v8s*)&hTh[(size_t)anode * 128 + 0 * 32 + q * 8];
  v8s ah1 = *(const v8s*)&hTh[(size_t)anode * 128 + 1 * 32 + q * 8];
  v8s ah2 = *(const v8s*)&hTh[(size_t)anode * 128 + 2 * 32 + q * 8];
  v8s ah3 = *(const v8s*)&hTh[(size_t)anode * 128 + 3 * 32 + q * 8];
  v8s al0 = *(const v8s*)&hTl[(size_t)anode * 128 + 0 * 32 + q * 8];
  v8s al1 = *(const v8s*)&hTl[(size_t)anode * 128 + 1 * 32 + q * 8];
  v8s al2 = *(const v8s*)&hTl[(size_t)anode * 128 + 2 * 32 + q * 8];
  v8s al3 = *(const v8s*)&hTl[(size_t)anode * 128 + 3 * 32 + q * 8];

  float racc1[4][4] = {{0.f}};
  float racc2[2][4] = {{0.f}};
  float racc3[2][4][3] = {{{0.f}}};
  float racc4[4][4] = {{0.f}};

  const int nrow = w * 16 + q * 4;

  {
    const int T = tile_of(cs, 0);
    async_lds16(&W2fh[(size_t)T * 2048 + tid * 8], &BstH[0][tid][0]);
    async_lds16(&W2fl[(size_t)T * 2048 + tid * 8], &BstL[0][tid][0]);
  }
  __syncthreads();

  #pragma unroll
  for (int t = 0; t < 18; ++t) {
    const int buf = t & 1;
    if (t < 17) {
      const int Tn = tile_of(cs, t + 1);
      async_lds16(&W2fh[(size_t)Tn * 2048 + tid * 8], &BstH[buf ^ 1][tid][0]);
      async_lds16(&W2fl[(size_t)Tn * 2048 + tid * 8], &BstL[buf ^ 1][tid][0]);
    }

    const int T = tile_of(cs, t);
    v8s bh0 = *(const v8s*)&BstH[buf][0 * 64 + l][0];
    v8s bh1 = *(const v8s*)&BstH[buf][1 * 64 + l][0];
    v8s bh2 = *(const v8s*)&BstH[buf][2 * 64 + l][0];
    v8s bh3 = *(const v8s*)&BstH[buf][3 * 64 + l][0];
    v8s bl0 = *(const v8s*)&BstL[buf][0 * 64 + l][0];
    v8s bl1 = *(const v8s*)&BstL[buf][1 * 64 + l][0];
    v8s bl2 = *(const v8s*)&BstL[buf][2 * 64 + l][0];
    v8s bl3 = *(const v8s*)&BstL[buf][3 * 64 + l][0];

    v4f a0 = (v4f){0.f, 0.f, 0.f, 0.f};
    v4f a1 = (v4f){0.f, 0.f, 0.f, 0.f};
    v4f a2 = (v4f){0.f, 0.f, 0.f, 0.f};
    a0 = __builtin_amdgcn_mfma_f32_16x16x32_bf16(ah0, bh0, a0, 0, 0, 0);
    a1 = __builtin_amdgcn_mfma_f32_16x16x32_bf16(al0, bh0, a1, 0, 0, 0);
    a2 = __builtin_amdgcn_mfma_f32_16x16x32_bf16(ah0, bl0, a2, 0, 0, 0);
    a0 = __builtin_amdgcn_mfma_f32_16x16x32_bf16(ah1, bh1, a0, 0, 0, 0);
    a1 = __builtin_amdgcn_mfma_f32_16x16x32_bf16(al1, bh1, a1, 0, 0, 0);
    a2 = __builtin_amdgcn_mfma_f32_16x16x32_bf16(ah1, bl1, a2, 0, 0, 0);
    a0 = __builtin_amdgcn_mfma_f32_16x16x32_bf16(ah2, bh2, a0, 0, 0, 0);
    a1 = __builtin_amdgcn_mfma_f32_16x16x32_bf16(al2, bh2, a1, 0, 0, 0);
    a2 = __builtin_amdgcn_mfma_f32_16x16x32_bf16(ah2, bl2, a2, 0, 0, 0);
    a0 = __builtin_amdgcn_mfma_f32_16x16x32_bf16(ah3, bh3, a0, 0, 0, 0);
    a1 = __builtin_amdgcn_mfma_f32_16x16x32_bf16(al3, bh3, a1, 0, 0, 0);
    a2 = __builtin_amdgcn_mfma_f32_16x16x32_bf16(ah3, bl3, a2, 0, 0, 0);
    a0 += a1; a0 += a2;
    const float bj = b2[T * 16 + cq];
    v4f tp = a0;
    tp[0] += bj; tp[1] += bj; tp[2] += bj; tp[3] += bj;

    if (t < 8) {
      const int i = cs * 2 + (t >> 2);
      const int m = t & 3;
      #pragma unroll
      for (int r = 0; r < 4; ++r)
        racc1[m][r] = fmaf(hf[(size_t)(g0 + nrow + r) * 160 + i], tp[r], racc1[m][r]);
    } else if (t < 12) {
      const int i = cs * 2 + ((t - 8) >> 1);
      const int m = (t - 8) & 1;
      #pragma unroll
      for (int r = 0; r < 4; ++r)
        racc2[m][r] = fmaf(hf[(size_t)(g0 + nrow + r) * 160 + i], tp[r], racc2[m][r]);
    } else if (t < 14) {
      const int m = (t - 12) & 1;
      #pragma unroll
      for (int r = 0; r < 4; ++r) {
        const float* xvp = hf + (size_t)(g0 + nrow + r) * 160 + 64 + 3 * cs;
        #pragma unroll
        for (int cc = 0; cc < 3; ++cc)
          racc3[m][r][cc] = fmaf(xvp[cc], tp[r], racc3[m][r][cc]);
      }
    } else {
      const int m = (t - 14) & 3;
      #pragma unroll
      for (int r = 0; r < 4; ++r)
        racc4[m][r] = fmaf(xvu[(size_t)(g0 + nrow + r) * 32 + cs], tp[r], racc4[m][r]);
    }
    __syncthreads();
  }

  // epilogue: owner-exclusive stores; sv folded in-register (owner of racc3
  // also owns racc2) — svS LDS eliminated, atomic loop contiguous.
  #pragma unroll
  for (int r = 0; r < 4; ++r) {
    const int n = nrow + r;
    float4 y1v = *(const float4*)&y1cw[(size_t)(g0 + n) * 4];
    #pragma unroll
    for (int m = 0; m < 4; ++m)
      valsS[n][m * 16 + cq] = racc1[m][r] + racc4[m][r];
    #pragma unroll
    for (int m = 0; m < 2; ++m) {
      const int o = m * 16 + cq;
      valsS[n][64 + 3 * o + 0] = fmaf(racc2[m][r], y1v.x, racc3[m][r][0]);
      valsS[n][64 + 3 * o + 1] = fmaf(racc2[m][r], y1v.y, racc3[m][r][1]);
      valsS[n][64 + 3 * o + 2] = fmaf(racc2[m][r], y1v.z, racc3[m][r][2]);
    }
  }
  __syncthreads();

  const float* vals = (const float*)valsS;
  float* vtgt = values8 + (size_t)p8 * 163840 + (size_t)g0 * 160;
  for (int idx = tid; idx < 10240; idx += 256)
    atomicAdd(&vtgt[idx], vals[idx]);
}

__device__ void gate_path(
    float* __restrict__ SH,
    const float* __restrict__ Pa, const float* __restrict__ Pe,
    const float* __restrict__ Pn,
    const unsigned short* __restrict__ W1fh, const unsigned short* __restrict__ W1fl,
    const float* __restrict__ b1, const float* __restrict__ W2v,
    const float* __restrict__ b2s, const float* __restrict__ y1cw,
    float* __restrict__ gate, int gate_idx) {
  const int b = gate_idx >> 6;
  const int e0 = (gate_idx & 63) * 2, e1 = e0 + 1;
  const int tid = threadIdx.x;

  float* Prow0 = SH;            // 128
  float* Prow1 = SH + 128;      // 128
  float (*gpre)[64] = (float(*)[64])(SH + 256);  // 2x64

  if (tid < 128) {
    float pa = Pa[b * 128 + tid];
    Prow0[tid] = pa + Pe[e0 * 128 + tid];
    Prow1[tid] = pa + Pe[e1 * 128 + tid];
  }
  __syncthreads();

  const int w = tid >> 6, l = tid & 63;
  const int q = l >> 4, cq = l & 15;
  const int node = w * 16 + cq;
  const float* pnrow = Pn + (size_t)(b * 64 + node) * 128;

  v4f acc0[8], acc1[8];
  #pragma unroll
  for (int t = 0; t < 8; ++t) {
    acc0[t] = (v4f){0.f, 0.f, 0.f, 0.f};
    acc1[t] = (v4f){0.f, 0.f, 0.f, 0.f};
  }

  #pragma unroll
  for (int ks = 0; ks < 4; ++ks) {
    const int k0 = ks * 32 + q * 8;
    float4 p0 = *(const float4*)(pnrow + k0);
    float4 p1 = *(const float4*)(pnrow + k0 + 4);
    float pv[8] = {p0.x, p0.y, p0.z, p0.w, p1.x, p1.y, p1.z, p1.w};
    float4 r00 = *(const float4*)(&Prow0[k0]);
    float4 r01 = *(const float4*)(&Prow0[k0 + 4]);
    float4 r10 = *(const float4*)(&Prow1[k0]);
    float4 r11 = *(const float4*)(&Prow1[k0 + 4]);
    float rv0[8] = {r00.x, r00.y, r00.z, r00.w, r01.x, r01.y, r01.z, r01.w};
    float rv1[8] = {r10.x, r10.y, r10.z, r10.w, r11.x, r11.y, r11.z, r11.w};
    v8s a0h, a0l, a1h, a1l;
    #pragma unroll
    for (int j = 0; j < 8; ++j) {
      short hs, ls;
      split_trunc(silu_f(pv[j] + rv0[j]), &hs, &ls);
      a0h[j] = hs; a0l[j] = ls;
      split_trunc(silu_f(pv[j] + rv1[j]), &hs, &ls);
      a1h[j] = hs; a1l[j] = ls;
    }
    #pragma unroll
    for (int t = 0; t < 8; ++t) {
      const size_t fb = (size_t)((ks * 8 + t) * 64 + l) * 8;
      v8s bh = *(const v8s*)&W1fh[fb];
      v8s bl = *(const v8s*)&W1fl[fb];
      acc0[t] = __builtin_amdgcn_mfma_f32_16x16x32_bf16(a0h, bh, acc0[t], 0, 0, 0);
      acc0[t] = __builtin_amdgcn_mfma_f32_16x16x32_bf16(a0l, bh, acc0[t], 0, 0, 0);
      acc0[t] = __builtin_amdgcn_mfma_f32_16x16x32_bf16(a0h, bl, acc0[t], 0, 0, 0);
      acc1[t] = __builtin_amdgcn_mfma_f32_16x16x32_bf16(a1h, bh, acc1[t], 0, 0, 0);
      acc1[t] = __builtin_amdgcn_mfma_f32_16x16x32_bf16(a1l, bh, acc1[t], 0, 0, 0);
      acc1[t] = __builtin_amdgcn_mfma_f32_16x16x32_bf16(a1h, bl, acc1[t], 0, 0, 0);
    }
  }

  float p00 = 0.f, p01 = 0.f, p02 = 0.f, p03 = 0.f;
  float p10 = 0.f, p11 = 0.f, p12 = 0.f, p13 = 0.f;
  #pragma unroll
  for (int t = 0; t < 8; ++t) {
    float bb = b1[t * 16 + cq];
    float wg = W2v[t * 16 + cq];
    p00 = fmaf(silu_f(acc0[t][0] + bb), wg, p00);
    p01 = fmaf(silu_f(acc0[t][1] + bb), wg, p01);
    p02 = fmaf(silu_f(acc0[t][2] + bb), wg, p02);
    p03 = fmaf(silu_f(acc0[t][3] + bb), wg, p03);
    p10 = fmaf(silu_f(acc1[t][0] + bb), wg, p10);
    p11 = fmaf(silu_f(acc1[t][1] + bb), wg, p11);
    p12 = fmaf(silu_f(acc1[t][2] + bb), wg, p12);
    p13 = fmaf(silu_f(acc1[t][3] + bb), wg, p13);
  }
  #pragma unroll
  for (int off = 1; off < 16; off <<= 1) {
    p00 += __shfl_xor(p00, off); p01 += __shfl_xor(p01, off);
    p02 += __shfl_xor(p02, off); p03 += __shfl_xor(p03, off);
    p10 += __shfl_xor(p10, off); p11 += __shfl_xor(p11, off);
    p12 += __shfl_xor(p12, off); p13 += __shfl_xor(p13, off);
  }
  if (cq == 0) {
    gpre[0][w * 16 + q * 4 + 0] = p00;
    gpre[0][w * 16 + q * 4 + 1] = p01;
    gpre[0][w * 16 + q * 4 + 2] = p02;
    gpre[0][w * 16 + q * 4 + 3] = p03;
    gpre[1][w * 16 + q * 4 + 0] = p10;
    gpre[1][w * 16 + q * 4 + 1] = p11;
    gpre[1][w * 16 + q * 4 + 2] = p12;
    gpre[1][w * 16 + q * 4 + 3] = p13;
  }
  __syncthreads();

  if (tid < 128) {
    const int ee = tid >> 6, ll = tid & 63;
    float gv = sigmoid_f(gpre[ee][ll] + b2s[0]);
    gv *= y1cw[(b * 64 + ll) * 4 + 3];
    float t2 = gv;
    #pragma unroll
    for (int off = 32; off > 0; off >>= 1) t2 += __shfl_xor(t2, off);
    float inv = 1.0f / fmaxf(t2, 1e-8f);
    const int e = (ee == 0) ? e0 : e1;
    gate[(size_t)(b * 128 + e) * 64 + ll] = gv * inv;
  }
}

__global__ void __launch_bounds__(256) k_mid(
    const unsigned short* __restrict__ hTh, const unsigned short* __restrict__ hTl,
    const unsigned short* __restrict__ W2fh, const unsigned short* __restrict__ W2fl,
    const float* __restrict__ b2, const float* __restrict__ hf,
    const float* __restrict__ xvu, const float* __restrict__ y1cw,
    float* __restrict__ values8,
    const float* __restrict__ Pa, const float* __restrict__ Pe,
    const float* __restrict__ Pn,
    const unsigned short* __restrict__ W1fh, const unsigned short* __restrict__ W1fl,
    const float* __restrict__ b1, const float* __restrict__ W2v,
    const float* __restrict__ b2s, float* __restrict__ gate) {
  __shared__ float SH[14336];  // 56KB union: tp uses all, gate uses 384 fl
  const int bid = blockIdx.x;
  const int third = bid / 3;
  if (bid - third * 3 == 0) {
    tp_path(SH, hTh, hTl, W2fh, W2fl, b2, hf, xvu, y1cw, values8, third);
  } else {
    gate_path(SH, Pa, Pe, Pn, W1fh, W1fl, b1, W2v, b2s, y1cw, gate,
              bid - third - 1);
  }
}

// ---------------------------------------------------------------------------
// K3b v2: agg + inv-feats with FUSED 8-way values8 reduce in the staging loop
// (k_reduce eliminated). grid=256: b=bid>>4, 8 energies/block. Reads 8x40KB
// per block (80MB total, L3-resident).
// ---------------------------------------------------------------------------
__global__ void __launch_bounds__(256) k_agg(
    const float* __restrict__ gate, const float* __restrict__ values8,
    float* __restrict__ inv_agg) {
  const int bid = blockIdx.x;
  const int b = bid >> 4;
  const int eg = bid & 15;
  const int tid = threadIdx.x;

  __shared__ float vS[10240];   // reduced values[b]
  __shared__ float gS[8][64];   // 8 gate rows
  __shared__ float aS[8][160];  // agg

  {
    float4* dst = (float4*)vS;
    const size_t base = (size_t)b * 10240;
    #pragma unroll
    for (int i = 0; i < 10; ++i) {
      const int s = tid + i * 256;
      float4 acc = make_float4(0.f, 0.f, 0.f, 0.f);
      #pragma unroll
      for (int p = 0; p < 8; ++p) {
        float4 v = *(const float4*)&values8[(size_t)p * 163840 + base + s * 4];
        acc.x += v.x; acc.y += v.y; acc.z += v.z; acc.w += v.w;
      }
      acc.x *= ALPHAF; acc.y *= ALPHAF; acc.z *= ALPHAF; acc.w *= ALPHAF;
      dst[s] = acc;
    }
    if (tid < 128)
      ((float4*)gS)[tid] =
          ((const float4*)(gate + ((size_t)b * 128 + eg * 8) * 64))[tid];
  }
  __syncthreads();

  #pragma unroll
  for (int it = 0; it < 5; ++it) {
    const int idx = it * 256 + tid;
    const int row = idx / 160;
    const int d = idx - row * 160;
    const float* gr = &gS[row][0];
    float a = 0.f;
    #pragma unroll 8
    for (int n = 0; n < 64; ++n) a = fmaf(gr[n], vS[n * 160 + d], a);
    aS[row][d] = a;
  }
  __syncthreads();

  for (int idx = tid; idx < 768; idx += 256) {
    const int row = idx / 96;
    const int ll = idx - row * 96;
    float rv;
    if (ll < 64) {
      rv = aS[row][ll];
    } else {
      const int o = ll - 64;
      float a0 = aS[row][64 + 3 * o + 0];
      float a1 = aS[row][64 + 3 * o + 1];
      float a2 = aS[row][64 + 3 * o + 2];
      rv = sqrtf((a0 * a0 + a1 * a1 + a2 * a2) * (1.0f / 3.0f) + 1e-8f);
    }
    inv_agg[((size_t)b * 128 + eg * 8 + row) * 96 + ll] = rv;
  }
}

// ---------------------------------------------------------------------------
// K4 v2: FUSED out-MLP (96->128 silu, 128->128 silu, 128->128) via MFMA.
// grid=128, 16 rows/block.
// ---------------------------------------------------------------------------
__global__ void __launch_bounds__(256) k_out(
    const float* __restrict__ X,
    const unsigned short* __restrict__ O0h, const unsigned short* __restrict__ O0l,
    const unsigned short* __restrict__ O1h, const unsigned short* __restrict__ O1l,
    const unsigned short* __restrict__ O2h, const unsigned short* __restrict__ O2l,
    const float* __restrict__ b0, const float* __restrict__ b1,
    const float* __restrict__ b2, float* __restrict__ out) {
  const int r0 = blockIdx.x * 16;
  const int tid = threadIdx.x;
  const int w = tid >> 6, l = tid & 63;
  const int q = l >> 4, cq = l & 15;
  const int t0 = 2 * w, t1 = 2 * w + 1;

  __shared__ float hS[16][132];

  v4f acc0 = (v4f){0.f, 0.f, 0.f, 0.f};
  v4f acc1 = (v4f){0.f, 0.f, 0.f, 0.f};
  {
    const float* xrow = X + (size_t)(r0 + cq) * 96 + q * 8;
    #pragma unroll
    for (int ks = 0; ks < 3; ++ks) {
      float4 p0 = *(const float4*)(xrow + ks * 32);
      float4 p1 = *(const float4*)(xrow + ks * 32 + 4);
      float xv[8] = {p0.x, p0.y, p0.z, p0.w, p1.x, p1.y, p1.z, p1.w};
      v8s avh, avl;
      #pragma unroll
      for (int j = 0; j < 8; ++j) {
        short hs, ls;
        split_trunc(xv[j], &hs, &ls);
        avh[j] = hs; avl[j] = ls;
      }
      v8s b0h = *(const v8s*)&O0h[((size_t)(ks * 8 + t0) * 64 + l) * 8];
      v8s b0l = *(const v8s*)&O0l[((size_t)(ks * 8 + t0) * 64 + l) * 8];
      v8s b1h = *(const v8s*)&O0h[((size_t)(ks * 8 + t1) * 64 + l) * 8];
      v8s b1l = *(const v8s*)&O0l[((size_t)(ks * 8 + t1) * 64 + l) * 8];
      acc0 = __builtin_amdgcn_mfma_f32_16x16x32_bf16(avh, b0h, acc0, 0, 0, 0);
      acc0 = __builtin_amdgcn_mfma_f32_16x16x32_bf16(avl, b0h, acc0, 0, 0, 0);
      acc0 = __builtin_amdgcn_mfma_f32_16x16x32_bf16(avh, b0l, acc0, 0, 0, 0);
      acc1 = __builtin_amdgcn_mfma_f32_16x16x32_bf16(avh, b1h, acc1, 0, 0, 0);
      acc1 = __builtin_amdgcn_mfma_f32_16x16x32_bf16(avl, b1h, acc1, 0, 0, 0);
      acc1 = __builtin_amdgcn_mfma_f32_16x16x32_bf16(avh, b1l, acc1, 0, 0, 0);
    }
  }
  {
    const float bb0 = b0[t0 * 16 + cq], bb1 = b0[t1 * 16 + cq];
    #pragma unroll
    for (int r = 0; r < 4; ++r) {
      hS[q * 4 + r][t0 * 16 + cq] = silu_f(acc0[r] + bb0);
      hS[q * 4 + r][t1 * 16 + cq] = silu_f(acc1[r] + bb1);
    }
  }
  __syncthreads();

  v8s a2h[4], a2l[4];
  #pragma unroll
  for (int ks = 0; ks < 4; ++ks) {
    float4 p0 = *(const float4*)&hS[cq][ks * 32 + q * 8];
    float4 p1 = *(const float4*)&hS[cq][ks * 32 + q * 8 + 4];
    float xv[8] = {p0.x, p0.y, p0.z, p0.w, p1.x, p1.y, p1.z, p1.w};
    #pragma unroll
    for (int j = 0; j < 8; ++j) {
      short hs, ls;
      split_trunc(xv[j], &hs, &ls);
      a2h[ks][j] = hs; a2l[ks][j] = ls;
    }
  }
  __syncthreads();
  acc0 = (v4f){0.f, 0.f, 0.f, 0.f};
  acc1 = (v4f){0.f, 0.f, 0.f, 0.f};
  #pragma unroll
  for (int ks = 0; ks < 4; ++ks) {
    v8s b0h = *(const v8s*)&O1h[((size_t)(ks * 8 + t0) * 64 + l) * 8];
    v8s b0l = *(const v8s*)&O1l[((size_t)(ks * 8 + t0) * 64 + l) * 8];
    v8s b1h = *(const v8s*)&O1h[((size_t)(ks * 8 + t1) * 64 + l) * 8];
    v8s b1l = *(const v8s*)&O1l[((size_t)(ks * 8 + t1) * 64 + l) * 8];
    acc0 = __builtin_amdgcn_mfma_f32_16x16x32_bf16(a2h[ks], b0h, acc0, 0, 0, 0);
    acc0 = __builtin_amdgcn_mfma_f32_16x16x32_bf16(a2l[ks], b0h, acc0, 0, 0, 0);
    acc0 = __builtin_amdgcn_mfma_f32_16x16x32_bf16(a2h[ks], b0l, acc0, 0, 0, 0);
    acc1 = __builtin_amdgcn_mfma_f32_16x16x32_bf16(a2h[ks], b1h, acc1, 0, 0, 0);
    acc1 = __builtin_amdgcn_mfma_f32_16x16x32_bf16(a2l[ks], b1h, acc1, 0, 0, 0);
    acc1 = __builtin_amdgcn_mfma_f32_16x16x32_bf16(a2h[ks], b1l, acc1, 0, 0, 0);
  }
  {
    const float bb0 = b1[t0 * 16 + cq], bb1 = b1[t1 * 16 + cq];
    #pragma unroll
    for (int r = 0; r < 4; ++r) {
      hS[q * 4 + r][t0 * 16 + cq] = silu_f(acc0[r] + bb0);
      hS[q * 4 + r][t1 * 16 + cq] = silu_f(acc1[r] + bb1);
    }
  }
  __syncthreads();

  #pragma unroll
  for (int ks = 0; ks < 4; ++ks) {
    float4 p0 = *(const float4*)&hS[cq][ks * 32 + q * 8];
    float4 p1 = *(const float4*)&hS[cq][ks * 32 + q * 8 + 4];
    float xv[8] = {p0.x, p0.y, p0.z, p0.w, p1.x, p1.y, p1.z, p1.w};
    #pragma unroll
    for (int j = 0; j < 8; ++j) {
      short hs, ls;
      split_trunc(xv[j], &hs, &ls);
      a2h[ks][j] = hs; a2l[ks][j] = ls;
    }
  }
  acc0 = (v4f){0.f, 0.f, 0.f, 0.f};
  acc1 = (v4f){0.f, 0.f, 0.f, 0.f};
  #pragma unroll
  for (int ks = 0; ks < 4; ++ks) {
    v8s b0h = *(const v8s*)&O2h[((size_t)(ks * 8 + t0) * 64 + l) * 8];
    v8s b0l = *(const v8s*)&O2l[((size_t)(ks * 8 + t0) * 64 + l) * 8];
    v8s b1h = *(const v8s*)&O2h[((size_t)(ks * 8 + t1) * 64 + l) * 8];
    v8s b1l = *(const v8s*)&O2l[((size_t)(ks * 8 + t1) * 64 + l) * 8];
    acc0 = __builtin_amdgcn_mfma_f32_16x16x32_bf16(a2h[ks], b0h, acc0, 0, 0, 0);
    acc0 = __builtin_amdgcn_mfma_f32_16x16x32_bf16(a2l[ks], b0h, acc0, 0, 0, 0);
    acc0 = __builtin_amdgcn_mfma_f32_16x16x32_bf16(a2h[ks], b0l, acc0, 0, 0, 0);
    acc1 = __builtin_amdgcn_mfma_f32_16x16x32_bf16(a2h[ks], b1h, acc1, 0, 0, 0);
    acc1 = __builtin_amdgcn_mfma_f32_16x16x32_bf16(a2l[ks], b1h, acc1, 0, 0, 0);
    acc1 = __builtin_amdgcn_mfma_f32_16x16x32_bf16(a2h[ks], b1l, acc1, 0, 0, 0);
  }
  {
    const float bb0 = b2[t0 * 16 + cq], bb1 = b2[t1 * 16 + cq];
    #pragma unroll
    for (int r = 0; r < 4; ++r) {
      out[(size_t)(r0 + q * 4 + r) * 128 + t0 * 16 + cq] = acc0[r] + bb0;
      out[(size_t)(r0 + q * 4 + r) * 128 + t1 * 16 + cq] = acc1[r] + bb1;
    }
  }
}

// ---------------------------------------------------------------------------
extern "C" void kernel_launch(void* const* d_in, const int* in_sizes, int n_in,
                              void* d_out, int out_size, void* d_ws, size_t ws_size,
                              hipStream_t stream) {
  const float* hf    = (const float*)d_in[0];
  const int*   z     = (const int*)  d_in[1];
  const float* pos   = (const float*)d_in[2];
  const float* e_feat= (const float*)d_in[4];
  const float* z_emb = (const float*)d_in[5];
  const float* vwW0  = (const float*)d_in[6];
  const float* vwb0  = (const float*)d_in[7];
  const float* vwW1  = (const float*)d_in[8];
  const float* vwb1  = (const float*)d_in[9];
  const float* vwW2  = (const float*)d_in[10];
  const float* vwb2  = (const float*)d_in[11];
  const float* scW0  = (const float*)d_in[12];
  const float* scb0  = (const float*)d_in[13];
  const float* scW1  = (const float*)d_in[14];
  const float* scb1  = (const float*)d_in[15];
  const float* scW2  = (const float*)d_in[16];
  const float* scb2  = (const float*)d_in[17];
  const float* oW0   = (const float*)d_in[18];
  const float* ob0   = (const float*)d_in[19];
  const float* oW1   = (const float*)d_in[20];
  const float* ob1   = (const float*)d_in[21];
  const float* oW2   = (const float*)d_in[22];
  const float* ob2   = (const float*)d_in[23];
  float* out = (float*)d_out;

  float* ws = (float*)d_ws;
  unsigned short* W2fh = (unsigned short*)(ws);            // 589824 fl
  unsigned short* W2fl = (unsigned short*)(ws + 589824);   // 589824 fl
  unsigned short* hTh  = (unsigned short*)(ws + 1179648);  // 65536 fl
  unsigned short* hTl  = (unsigned short*)(ws + 1245184);  // 65536 fl
  float* Pn     = ws + 1310720;   // 131072
  float* Pa     = Pn + 131072;    // 2048
  float* Pe     = Pa + 2048;      // 16384
  float* xvu    = Pe + 16384;     // 32768
  float* y1cw   = xvu + 32768;    // 4096
  float* values = y1cw + 4096;    // 163840 (now unused; layout kept)
  float* gate   = values + 163840;// 131072 (region reserved 196608)
  unsigned short* W1fh = (unsigned short*)(gate + 196608);  // 8192 fl
  unsigned short* W1fl = (unsigned short*)(gate + 196608 + 8192);
  float* values8 = gate + 196608 + 16384;  // 8*163840 fl
  unsigned short* Ob = (unsigned short*)(values8 + 8 * 163840);
  unsigned short* O0h = Ob;
  unsigned short* O0l = Ob + 12288;
  unsigned short* O1h = Ob + 24576;
  unsigned short* O1l = Ob + 40960;
  unsigned short* O2h = Ob + 57344;
  unsigned short* O2l = Ob + 73728;
  float* invagg = (float*)(Ob + 90112);  // 196608 fl

  hipMemsetAsync(values8, 0, 8 * 163840 * sizeof(float), stream);

  k_front<<<1182, 256, 0, stream>>>(
      vwW2, W2fh, W2fl,
      hf, z, pos, z_emb, vwW0, vwb0, vwW1, vwb1, scW0,
      hTh, hTl, Pn, Pa, xvu, y1cw,
      scW1, W1fh, W1fl, oW0, oW1, oW2,
      O0h, O0l, O1h, O1l, O2h, O2l,
      e_feat, scb0, Pe);
  k_mid<<<1536, 256, 0, stream>>>(hTh, hTl, W2fh, W2fl, vwb2, hf, xvu, y1cw,
                                  values8, Pa, Pe, Pn, W1fh, W1fl, scb1, scW2,
                                  scb2, gate);
  k_agg<<<256, 256, 0, stream>>>(gate, values8, invagg);
  k_out<<<128, 256, 0, stream>>>(invagg, O0h, O0l, O1h, O1l, O2h, O2l,
                                 ob0, ob1, ob2, out);
}